// Round 4
// baseline (345.042 us; speedup 1.0000x reference)
//
#include <hip/hip_runtime.h>

typedef __bf16 bf16;
typedef __bf16 bf16x4_t __attribute__((ext_vector_type(4)));
typedef __bf16 bf16x8_t __attribute__((ext_vector_type(8)));
typedef float f32x4_t __attribute__((ext_vector_type(4)));

#define MFMA16(a, b, c) __builtin_amdgcn_mfma_f32_16x16x32_bf16(a, b, c, 0, 0, 0)

// K=16 16x16 MFMA: A[m=l15][k=quad*4+j], B[n=l15][k=quad*4+j], C row=quad*4+r col=l15
static __device__ __forceinline__ f32x4_t mfma_k16(bf16x4_t a, bf16x4_t b, f32x4_t c) {
#if __has_builtin(__builtin_amdgcn_mfma_f32_16x16x16bf16_1k)
    typedef short s16x4_t __attribute__((ext_vector_type(4)));
    return __builtin_amdgcn_mfma_f32_16x16x16bf16_1k(
        __builtin_bit_cast(s16x4_t, a), __builtin_bit_cast(s16x4_t, b), c, 0, 0, 0);
#else
    // zero-padded K=32 fallback: k=quad*8+j, j<4 holds data, j>=4 zero on BOTH operands
    bf16x8_t az = {}, bz = {};
    az[0] = a[0]; az[1] = a[1]; az[2] = a[2]; az[3] = a[3];
    bz[0] = b[0]; bz[1] = b[1]; bz[2] = b[2]; bz[3] = b[3];
    return MFMA16(az, bz, c);
#endif
}

// ---------------- f32 -> bf16 cast of the 3 weight matrices, one kernel ----------------
__global__ void cast3_k(const float* __restrict__ a, const float* __restrict__ b,
                        const float* __restrict__ c, bf16* __restrict__ da,
                        bf16* __restrict__ db, bf16* __restrict__ dc) {
    int i = blockIdx.x * blockDim.x + threadIdx.x; // 0 .. 2304*512
    if (i < 786432) da[i] = (bf16)a[i];
    else if (i < 1048576) db[i - 786432] = (bf16)b[i - 786432];
    else if (i < 1179648) dc[i - 1048576] = (bf16)c[i - 1048576];
}

// ---------------- conditional layernorm -> xn bf16 (one wave per token) ----------------
__global__ __launch_bounds__(256) void ln_k(const float* __restrict__ x,
                                            const int* __restrict__ gt,
                                            const float* __restrict__ tfg,
                                            const float* __restrict__ tfb,
                                            const float* __restrict__ tgg,
                                            const float* __restrict__ tgb,
                                            bf16* __restrict__ xn) {
    int wid = threadIdx.x >> 6, lane = threadIdx.x & 63;
    int t = blockIdx.x * 4 + wid;
    const float4* xr = (const float4*)(x + (size_t)t * 512);
    float4 a = xr[lane * 2], b = xr[lane * 2 + 1];
    float s = (a.x + a.y) + (a.z + a.w) + (b.x + b.y) + (b.z + b.w);
    float sq = a.x * a.x + a.y * a.y + a.z * a.z + a.w * a.w +
               b.x * b.x + b.y * b.y + b.z * b.z + b.w * b.w;
    for (int m = 1; m < 64; m <<= 1) {
        s += __shfl_xor(s, m, 64);
        sq += __shfl_xor(sq, m, 64);
    }
    float mean = s * (1.f / 512.f);
    float var = fmaxf(sq * (1.f / 512.f) - mean * mean, 0.f);
    float rstd = rsqrtf(var + 1e-5f);
    int g = gt[t];
    float4 o0, o1;
    if (g < 2) {
        const float4* gp = (const float4*)(g ? tgg : tfg);
        const float4* bp = (const float4*)(g ? tgb : tfb);
        float4 g0 = gp[lane * 2], g1 = gp[lane * 2 + 1];
        float4 b0 = bp[lane * 2], b1 = bp[lane * 2 + 1];
        o0.x = (a.x - mean) * rstd * g0.x + b0.x;
        o0.y = (a.y - mean) * rstd * g0.y + b0.y;
        o0.z = (a.z - mean) * rstd * g0.z + b0.z;
        o0.w = (a.w - mean) * rstd * g0.w + b0.w;
        o1.x = (b.x - mean) * rstd * g1.x + b1.x;
        o1.y = (b.y - mean) * rstd * g1.y + b1.y;
        o1.z = (b.z - mean) * rstd * g1.z + b1.z;
        o1.w = (b.w - mean) * rstd * g1.w + b1.w;
    } else {
        o0 = a; o1 = b;
    }
    bf16* xo = xn + (size_t)t * 512 + lane * 8;
    bf16x4_t p0, p1;
    p0[0] = (bf16)o0.x; p0[1] = (bf16)o0.y; p0[2] = (bf16)o0.z; p0[3] = (bf16)o0.w;
    p1[0] = (bf16)o1.x; p1[1] = (bf16)o1.y; p1[2] = (bf16)o1.z; p1[3] = (bf16)o1.w;
    *(bf16x4_t*)xo = p0;
    *(bf16x4_t*)(xo + 4) = p1;
}

// ---------------- NT GEMM: C[M,N] = A[M,K=512] * B[N,K=512]^T, bf16 MFMA ----------------
// EPI 0: +bias, scatter qkv (q scaled by 0.125*log2e, v transposed to [BH,64,S])
// EPI 1: +bias, +xn residual -> xr fp32 (xrf) + xr bf16 (p0)
// EPI 2: +bias, SiLU -> h bf16 (p0), N=256
template <int EPI>
__global__ __launch_bounds__(256) void gemm_k(const bf16* __restrict__ A,
                                              const bf16* __restrict__ B,
                                              const float* __restrict__ bias,
                                              bf16* __restrict__ p0,
                                              bf16* __restrict__ p1,
                                              bf16* __restrict__ p2,
                                              const bf16* __restrict__ xn,
                                              float* __restrict__ xrf) {
    int m0 = blockIdx.x * 128, n0 = blockIdx.y * 128;
    int tid = threadIdx.x;
    int lane = tid & 63, w = tid >> 6;
    int quad = lane >> 4, l15 = lane & 15;
    int wm = (w >> 1) * 64, wn = (w & 1) * 64;
    __shared__ bf16 As[128 * 72];
    __shared__ bf16 Bs[128 * 72];
    f32x4_t acc[4][4] = {};
    int srow = tid >> 3, ssub = tid & 7;
    const bf16* Ab = A + (size_t)(m0 + srow) * 512 + ssub * 8;
    const bf16* Bb = B + (size_t)(n0 + srow) * 512 + ssub * 8;
    uint4 pa[4], pb[4];
    auto gload = [&](int s) {
        int k0 = s * 64;
#pragma unroll
        for (int i = 0; i < 4; ++i) {
            pa[i] = *(const uint4*)(Ab + (size_t)(i * 32) * 512 + k0);
            pb[i] = *(const uint4*)(Bb + (size_t)(i * 32) * 512 + k0);
        }
    };
    auto sstore = [&]() {
#pragma unroll
        for (int i = 0; i < 4; ++i) {
            *(uint4*)&As[(i * 32 + srow) * 72 + ssub * 8] = pa[i];
            *(uint4*)&Bs[(i * 32 + srow) * 72 + ssub * 8] = pb[i];
        }
    };
    gload(0);
    sstore();
    for (int s = 0; s < 8; ++s) {
        __syncthreads();
        if (s < 7) gload(s + 1);
#pragma unroll
        for (int ks = 0; ks < 2; ++ks) {
            bf16x8_t af[4], bfr[4];
            int koff = ks * 32 + quad * 8;
#pragma unroll
            for (int mt = 0; mt < 4; ++mt)
                af[mt] = *(const bf16x8_t*)&As[(wm + mt * 16 + l15) * 72 + koff];
#pragma unroll
            for (int nt = 0; nt < 4; ++nt)
                bfr[nt] = *(const bf16x8_t*)&Bs[(wn + nt * 16 + l15) * 72 + koff];
#pragma unroll
            for (int mt = 0; mt < 4; ++mt)
#pragma unroll
                for (int nt = 0; nt < 4; ++nt)
                    acc[mt][nt] = MFMA16(af[mt], bfr[nt], acc[mt][nt]);
        }
        __syncthreads();
        if (s < 7) sstore();
    }
    // epilogue: C layout col=lane&15, row=quad*4+r (m89-verified)
#pragma unroll
    for (int mt = 0; mt < 4; ++mt) {
#pragma unroll
        for (int nt = 0; nt < 4; ++nt) {
            int gcol = n0 + wn + nt * 16 + l15;
            float bcol = bias[gcol];
#pragma unroll
            for (int r = 0; r < 4; ++r) {
                int grow = m0 + wm + mt * 16 + quad * 4 + r;
                float v = acc[mt][nt][r] + bcol;
                if constexpr (EPI == 0) {
                    int which = gcol >> 9;
                    int d = gcol & 511;
                    int hh = d >> 6, hd = d & 63;
                    int b = grow >> 11, ssi = grow & 2047;
                    size_t bh = (size_t)(b * 8 + hh);
                    if (which == 0) {
                        p0[(bh * 2048 + ssi) * 64 + hd] = (bf16)(v * 0.180336880111f); // 0.125*log2(e)
                    } else if (which == 1) {
                        p1[(bh * 2048 + ssi) * 64 + hd] = (bf16)v;
                    } else {
                        p2[(bh * 64 + hd) * 2048 + ssi] = (bf16)v; // V transposed
                    }
                } else if constexpr (EPI == 1) {
                    size_t idx = (size_t)grow * 512 + gcol;
                    float xv = v + (float)xn[idx];
                    xrf[idx] = xv;
                    p0[idx] = (bf16)xv;
                } else {
                    float sv = v / (1.f + __expf(-v)); // SiLU
                    p0[(size_t)grow * 256 + gcol] = (bf16)sv;
                }
            }
        }
    }
    (void)p1; (void)p2; (void)xn; (void)xrf;
}

// ---------------- flash attention: S^T formulation, P stays in registers ----------------
// q,k: [BH,S,64] bf16 (q pre-scaled by 0.125*log2e); vt: [BH,64,S]
// pO: [split][BH,S,64] bf16 un-normalized; pL: [split][BH,S] f32 row sums
// S^T = K·Q^T: C-layout gives lane {kv=quad*4+r, q=l15} == A-operand layout of K=16 MFMA.
__global__ __launch_bounds__(256) void attn_k(const bf16* __restrict__ q,
                                              const bf16* __restrict__ k,
                                              const bf16* __restrict__ vt,
                                              bf16* __restrict__ pO,
                                              float* __restrict__ pL,
                                              int nsplit) {
    int bh = blockIdx.y;
    int q0 = blockIdx.x * 128;
    int sz = blockIdx.z;
    int tiles = 32 / nsplit;
    int kt0 = sz * tiles;
    int tid = threadIdx.x;
    int lane = tid & 63, w = tid >> 6;
    int quad = lane >> 4, l15 = lane & 15;
    __shared__ bf16 Ks[64 * 72];
    __shared__ bf16 Vs[64 * 72];
    const bf16* qb = q + (size_t)bh * 2048 * 64;
    const bf16* kb = k + (size_t)bh * 2048 * 64;
    const bf16* vb = vt + (size_t)bh * 64 * 2048;
    bf16x8_t qf[2][2]; // B-operand: n=q (l15), k=d (quad*8+j)
#pragma unroll
    for (int qt = 0; qt < 2; ++qt)
#pragma unroll
        for (int ks = 0; ks < 2; ++ks)
            qf[qt][ks] = *(const bf16x8_t*)(qb + (size_t)(q0 + w * 32 + qt * 16 + l15) * 64 + ks * 32 + quad * 8);
    bf16x4_t ones4;
#pragma unroll
    for (int i = 0; i < 4; ++i) ones4[i] = (bf16)1.0f;
    f32x4_t oacc[2][4] = {};
    f32x4_t lacc[2] = {};
    int srow = tid >> 3, ssub = tid & 7;
    uint4 pk[2], pv[2];
    auto gload = [&](int kt) {
        int kbase = kt * 64;
#pragma unroll
        for (int i = 0; i < 2; ++i) {
            int row = i * 32 + srow;
            pk[i] = *(const uint4*)(kb + (size_t)(kbase + row) * 64 + ssub * 8);
            pv[i] = *(const uint4*)(vb + (size_t)row * 2048 + kbase + ssub * 8);
        }
    };
    auto sstore = [&]() {
#pragma unroll
        for (int i = 0; i < 2; ++i) {
            int row = i * 32 + srow;
            *(uint4*)&Ks[row * 72 + ssub * 8] = pk[i];
            *(uint4*)&Vs[row * 72 + ssub * 8] = pv[i];
        }
    };
    gload(kt0);
    for (int kt = kt0; kt < kt0 + tiles; ++kt) {
        __syncthreads(); // previous tile's compute done
        sstore();
        __syncthreads();
        if (kt + 1 < kt0 + tiles) gload(kt + 1); // overlaps with compute below
        // S^T[kv][q] via MFMA(A=K, B=Q)
        f32x4_t sacc[4][2] = {};
#pragma unroll
        for (int ks = 0; ks < 2; ++ks) {
            int koff = ks * 32 + quad * 8;
            bf16x8_t kf[4];
#pragma unroll
            for (int nt = 0; nt < 4; ++nt)
                kf[nt] = *(const bf16x8_t*)&Ks[(nt * 16 + l15) * 72 + koff];
#pragma unroll
            for (int nt = 0; nt < 4; ++nt)
#pragma unroll
                for (int qt = 0; qt < 2; ++qt)
                    sacc[nt][qt] = MFMA16(kf[nt], qf[qt][ks], sacc[nt][qt]);
        }
        // P = exp2(S^T) -> registers, already in K=16 A-operand layout
        bf16x4_t pf[4][2];
#pragma unroll
        for (int nt = 0; nt < 4; ++nt)
#pragma unroll
            for (int qt = 0; qt < 2; ++qt)
#pragma unroll
                for (int r = 0; r < 4; ++r)
                    pf[nt][qt][r] = (bf16)exp2f(sacc[nt][qt][r]);
        // O += P·V ; l += P·1  (K=16 MFMAs per 16-kv subtile)
#pragma unroll
        for (int nt = 0; nt < 4; ++nt) {
            bf16x4_t vf[4];
#pragma unroll
            for (int dt = 0; dt < 4; ++dt)
                vf[dt] = *(const bf16x4_t*)&Vs[(dt * 16 + l15) * 72 + nt * 16 + quad * 4];
#pragma unroll
            for (int qt = 0; qt < 2; ++qt) {
#pragma unroll
                for (int dt = 0; dt < 4; ++dt)
                    oacc[qt][dt] = mfma_k16(pf[nt][qt], vf[dt], oacc[qt][dt]);
                lacc[qt] = mfma_k16(pf[nt][qt], ones4, lacc[qt]);
            }
        }
    }
    // write partial O (un-normalized bf16) + row sums
    size_t obase = ((size_t)(sz * 32 + bh) * 2048 + q0);
#pragma unroll
    for (int qt = 0; qt < 2; ++qt)
#pragma unroll
        for (int r = 0; r < 4; ++r) {
            int row = w * 32 + qt * 16 + quad * 4 + r;
#pragma unroll
            for (int dt = 0; dt < 4; ++dt)
                pO[(obase + row) * 64 + dt * 16 + l15] = (bf16)oacc[qt][dt][r];
            if (l15 == 0) pL[obase + row] = lacc[qt][r];
        }
}

// ---------------- combine splits: o[t,512] = sum_s O_s / sum_s l_s ----------------
__global__ __launch_bounds__(256) void comb_k(const bf16* __restrict__ pO,
                                              const float* __restrict__ pL,
                                              bf16* __restrict__ o, int nsplit) {
    int i = blockIdx.x * 256 + threadIdx.x; // * 4 elems, total 32*2048*64
    int hd = (i & 15) * 4;
    int s = (i >> 4) & 2047;
    int bh = i >> 15;
    float l = 0.f;
    float acc[4] = {};
    for (int sp = 0; sp < nsplit; ++sp) {
        size_t r = (size_t)(sp * 32 + bh) * 2048 + s;
        l += pL[r];
        bf16x4_t a = *(const bf16x4_t*)(pO + r * 64 + hd);
#pragma unroll
        for (int j = 0; j < 4; ++j) acc[j] += (float)a[j];
    }
    float inv = 1.f / l;
    int bb = bh >> 3, hh = bh & 7;
    bf16x4_t ov;
#pragma unroll
    for (int j = 0; j < 4; ++j) ov[j] = (bf16)(acc[j] * inv);
    *(bf16x4_t*)(o + ((size_t)(bb * 2048 + s) * 512) + hh * 64 + hd) = ov;
}

// ---------------- gate: strength = sigmoid(h . w2 + b2); out = xr * strength ----------------
__global__ __launch_bounds__(256) void gate_k(const bf16* __restrict__ h,
                                              const float* __restrict__ w2,
                                              const float* __restrict__ b2,
                                              const float* __restrict__ xrf,
                                              float* __restrict__ out) {
    int t = blockIdx.x * 4 + (threadIdx.x >> 6);
    int lane = threadIdx.x & 63;
    const bf16* hr = h + (size_t)t * 256;
    bf16x4_t hv = *(const bf16x4_t*)(hr + lane * 4);
    float4 wv = *(const float4*)(w2 + lane * 4);
    float dot = (float)hv[0] * wv.x + (float)hv[1] * wv.y + (float)hv[2] * wv.z + (float)hv[3] * wv.w;
    for (int m = 1; m < 64; m <<= 1) dot += __shfl_xor(dot, m, 64);
    float st = 1.f / (1.f + __expf(-(dot + b2[0])));
    const float4* x4 = (const float4*)(xrf + (size_t)t * 512);
    float4* o4 = (float4*)(out + (size_t)t * 512);
#pragma unroll
    for (int j = 0; j < 2; ++j) {
        float4 xv = x4[lane * 2 + j];
        float4 ov;
        ov.x = xv.x * st; ov.y = xv.y * st; ov.z = xv.z * st; ov.w = xv.w * st;
        o4[lane * 2 + j] = ov;
    }
}

extern "C" void kernel_launch(void* const* d_in, const int* in_sizes, int n_in,
                              void* d_out, int out_size, void* d_ws, size_t ws_size,
                              hipStream_t stream) {
    const float* x    = (const float*)d_in[0];
    const int*   gt   = (const int*)d_in[1];
    const float* tfg  = (const float*)d_in[2];
    const float* tfb  = (const float*)d_in[3];
    const float* tgg  = (const float*)d_in[4];
    const float* tgb  = (const float*)d_in[5];
    const float* Wqkv = (const float*)d_in[6];
    const float* bqkv = (const float*)d_in[7];
    const float* Wout = (const float*)d_in[8];
    const float* bout = (const float*)d_in[9];
    const float* W1   = (const float*)d_in[10];
    const float* b1   = (const float*)d_in[11];
    const float* w2   = (const float*)d_in[12];
    const float* b2   = (const float*)d_in[13];
    float* out = (float*)d_out;
    char* ws = (char*)d_ws;

    const size_t MB = 1024 * 1024;
    // weights + pL in [0, 4MB)
    bf16*  wq  = (bf16*)(ws + 0);                          // 1.5 MB [1536,512]
    bf16*  wo  = (bf16*)(ws + 1536 * 512 * 2);             // 0.5 MB [512,512]
    bf16*  w1b = (bf16*)(ws + (1536 + 512) * 512 * 2);     // 0.25 MB [256,512]
    float* pL  = (float*)(ws + 2304 * 512 * 2);            // <=1 MB [nsplit][32,2048]
    // activations (aliased by liveness)
    bf16*  xn  = (bf16*)(ws + 4 * MB);   //  8 MB [8192,512]            live: ln..gemm1
    bf16*  q   = (bf16*)(ws + 12 * MB);  //  8 MB [32,2048,64]          live: gemm0..attn
    bf16*  o   = (bf16*)(ws + 12 * MB);  //  8 MB [8192,512]   (=q)     live: comb..gemm1
    bf16*  kk  = (bf16*)(ws + 20 * MB);  //  8 MB [32,2048,64]          live: gemm0..attn
    bf16*  vt  = (bf16*)(ws + 28 * MB);  //  8 MB [32,64,2048]          live: gemm0..attn
    float* xrf = (float*)(ws + 20 * MB); // 16 MB [8192,512]  (=kk,vt)  live: gemm1..gate
    bf16*  pO  = (bf16*)(ws + 36 * MB);  //  8*nsplit MB                live: attn..comb
    bf16*  xrb = (bf16*)(ws + 36 * MB);  //  8 MB [8192,512]  (=pO)     live: gemm1..gemm2
    bf16*  h   = (bf16*)(ws + 44 * MB);  //  4 MB [8192,256]  (=pO)     live: gemm2..gate

    int nsplit = (ws_size >= 69 * MB) ? 4 : 2; // ws_size constant across calls -> same work every call

    cast3_k<<<4608, 256, 0, stream>>>(Wqkv, Wout, W1, wq, wo, w1b);
    ln_k<<<2048, 256, 0, stream>>>(x, gt, tfg, tfb, tgg, tgb, xn);
    gemm_k<0><<<dim3(64, 12), 256, 0, stream>>>(xn, wq, bqkv, q, kk, vt, nullptr, nullptr);
    attn_k<<<dim3(16, 32, nsplit), 256, 0, stream>>>(q, kk, vt, pO, pL, nsplit);
    comb_k<<<4096, 256, 0, stream>>>(pO, pL, o, nsplit);
    gemm_k<1><<<dim3(64, 4), 256, 0, stream>>>(o, wo, bout, xrb, nullptr, nullptr, xn, xrf);
    gemm_k<2><<<dim3(64, 2), 256, 0, stream>>>(xrb, w1b, b1, h, nullptr, nullptr, nullptr, nullptr);
    gate_k<<<2048, 256, 0, stream>>>(h, w2, b2, xrf, out);
    (void)in_sizes; (void)n_in; (void)out_size;
}

// Round 5
// 336.137 us; speedup vs baseline: 1.0265x; 1.0265x over previous
//
#include <hip/hip_runtime.h>

typedef __bf16 bf16;
typedef __bf16 bf16x4_t __attribute__((ext_vector_type(4)));
typedef __bf16 bf16x8_t __attribute__((ext_vector_type(8)));
typedef float f32x4_t __attribute__((ext_vector_type(4)));

#define MFMA16(a, b, c) __builtin_amdgcn_mfma_f32_16x16x32_bf16(a, b, c, 0, 0, 0)

// K=16 16x16 MFMA: A[m=l15][k=quad*4+j], B[n=l15][k=quad*4+j], C row=quad*4+r col=l15
static __device__ __forceinline__ f32x4_t mfma_k16(bf16x4_t a, bf16x4_t b, f32x4_t c) {
#if __has_builtin(__builtin_amdgcn_mfma_f32_16x16x16bf16_1k)
    typedef short s16x4_t __attribute__((ext_vector_type(4)));
    return __builtin_amdgcn_mfma_f32_16x16x16bf16_1k(
        __builtin_bit_cast(s16x4_t, a), __builtin_bit_cast(s16x4_t, b), c, 0, 0, 0);
#else
    bf16x8_t az = {}, bz = {};
    az[0] = a[0]; az[1] = a[1]; az[2] = a[2]; az[3] = a[3];
    bz[0] = b[0]; bz[1] = b[1]; bz[2] = b[2]; bz[3] = b[3];
    return MFMA16(az, bz, c);
#endif
}

// ---------------- fused: weight casts (blocks 0..4607) + conditional LN (4608..6655) ----------------
__global__ __launch_bounds__(256) void castln_k(const float* __restrict__ Wqkv,
                                                const float* __restrict__ Wout,
                                                const float* __restrict__ W1,
                                                bf16* __restrict__ wq,
                                                bf16* __restrict__ wo,
                                                bf16* __restrict__ w1b,
                                                const float* __restrict__ x,
                                                const int* __restrict__ gt,
                                                const float* __restrict__ tfg,
                                                const float* __restrict__ tfb,
                                                const float* __restrict__ tgg,
                                                const float* __restrict__ tgb,
                                                bf16* __restrict__ xn) {
    if (blockIdx.x < 4608) {
        int i = blockIdx.x * 256 + threadIdx.x;
        if (i < 786432) wq[i] = (bf16)Wqkv[i];
        else if (i < 1048576) wo[i - 786432] = (bf16)Wout[i - 786432];
        else if (i < 1179648) w1b[i - 1048576] = (bf16)W1[i - 1048576];
        return;
    }
    int wid = threadIdx.x >> 6, lane = threadIdx.x & 63;
    int t = (blockIdx.x - 4608) * 4 + wid;
    const float4* xr = (const float4*)(x + (size_t)t * 512);
    float4 a = xr[lane * 2], b = xr[lane * 2 + 1];
    float s = (a.x + a.y) + (a.z + a.w) + (b.x + b.y) + (b.z + b.w);
    float sq = a.x * a.x + a.y * a.y + a.z * a.z + a.w * a.w +
               b.x * b.x + b.y * b.y + b.z * b.z + b.w * b.w;
    for (int m = 1; m < 64; m <<= 1) {
        s += __shfl_xor(s, m, 64);
        sq += __shfl_xor(sq, m, 64);
    }
    float mean = s * (1.f / 512.f);
    float var = fmaxf(sq * (1.f / 512.f) - mean * mean, 0.f);
    float rstd = rsqrtf(var + 1e-5f);
    int g = gt[t];
    float4 o0, o1;
    if (g < 2) {
        const float4* gp = (const float4*)(g ? tgg : tfg);
        const float4* bp = (const float4*)(g ? tgb : tfb);
        float4 g0 = gp[lane * 2], g1 = gp[lane * 2 + 1];
        float4 b0 = bp[lane * 2], b1 = bp[lane * 2 + 1];
        o0.x = (a.x - mean) * rstd * g0.x + b0.x;
        o0.y = (a.y - mean) * rstd * g0.y + b0.y;
        o0.z = (a.z - mean) * rstd * g0.z + b0.z;
        o0.w = (a.w - mean) * rstd * g0.w + b0.w;
        o1.x = (b.x - mean) * rstd * g1.x + b1.x;
        o1.y = (b.y - mean) * rstd * g1.y + b1.y;
        o1.z = (b.z - mean) * rstd * g1.z + b1.z;
        o1.w = (b.w - mean) * rstd * g1.w + b1.w;
    } else {
        o0 = a; o1 = b;
    }
    bf16* xo = xn + (size_t)t * 512 + lane * 8;
    bf16x4_t p0, p1;
    p0[0] = (bf16)o0.x; p0[1] = (bf16)o0.y; p0[2] = (bf16)o0.z; p0[3] = (bf16)o0.w;
    p1[0] = (bf16)o1.x; p1[1] = (bf16)o1.y; p1[2] = (bf16)o1.z; p1[3] = (bf16)o1.w;
    *(bf16x4_t*)xo = p0;
    *(bf16x4_t*)(xo + 4) = p1;
}

// ---------------- QKV GEMM: C[M,1536] = xn * Wqkv^T, scatter epilogue ----------------
__global__ __launch_bounds__(256) void gemmqkv_k(const bf16* __restrict__ A,
                                                 const bf16* __restrict__ B,
                                                 const float* __restrict__ bias,
                                                 bf16* __restrict__ q,
                                                 bf16* __restrict__ kk,
                                                 bf16* __restrict__ vt) {
    int m0 = blockIdx.x * 128, n0 = blockIdx.y * 128;
    int tid = threadIdx.x;
    int lane = tid & 63, w = tid >> 6;
    int quad = lane >> 4, l15 = lane & 15;
    int wm = (w >> 1) * 64, wn = (w & 1) * 64;
    __shared__ bf16 As[128 * 72];
    __shared__ bf16 Bs[128 * 72];
    f32x4_t acc[4][4] = {};
    int srow = tid >> 3, ssub = tid & 7;
    const bf16* Ab = A + (size_t)(m0 + srow) * 512 + ssub * 8;
    const bf16* Bb = B + (size_t)(n0 + srow) * 512 + ssub * 8;
    uint4 pa[4], pb[4];
    auto gload = [&](int s) {
        int k0 = s * 64;
#pragma unroll
        for (int i = 0; i < 4; ++i) {
            pa[i] = *(const uint4*)(Ab + (size_t)(i * 32) * 512 + k0);
            pb[i] = *(const uint4*)(Bb + (size_t)(i * 32) * 512 + k0);
        }
    };
    auto sstore = [&]() {
#pragma unroll
        for (int i = 0; i < 4; ++i) {
            *(uint4*)&As[(i * 32 + srow) * 72 + ssub * 8] = pa[i];
            *(uint4*)&Bs[(i * 32 + srow) * 72 + ssub * 8] = pb[i];
        }
    };
    gload(0);
    sstore();
    for (int s = 0; s < 8; ++s) {
        __syncthreads();
        if (s < 7) gload(s + 1);
#pragma unroll
        for (int ks = 0; ks < 2; ++ks) {
            bf16x8_t af[4], bfr[4];
            int koff = ks * 32 + quad * 8;
#pragma unroll
            for (int mt = 0; mt < 4; ++mt)
                af[mt] = *(const bf16x8_t*)&As[(wm + mt * 16 + l15) * 72 + koff];
#pragma unroll
            for (int nt = 0; nt < 4; ++nt)
                bfr[nt] = *(const bf16x8_t*)&Bs[(wn + nt * 16 + l15) * 72 + koff];
#pragma unroll
            for (int mt = 0; mt < 4; ++mt)
#pragma unroll
                for (int nt = 0; nt < 4; ++nt)
                    acc[mt][nt] = MFMA16(af[mt], bfr[nt], acc[mt][nt]);
        }
        __syncthreads();
        if (s < 7) sstore();
    }
#pragma unroll
    for (int mt = 0; mt < 4; ++mt) {
#pragma unroll
        for (int nt = 0; nt < 4; ++nt) {
            int gcol = n0 + wn + nt * 16 + l15;
            float bcol = bias[gcol];
#pragma unroll
            for (int r = 0; r < 4; ++r) {
                int grow = m0 + wm + mt * 16 + quad * 4 + r;
                float v = acc[mt][nt][r] + bcol;
                int which = gcol >> 9;
                int d = gcol & 511;
                int hh = d >> 6, hd = d & 63;
                int b = grow >> 11, ssi = grow & 2047;
                size_t bh = (size_t)(b * 8 + hh);
                if (which == 0) {
                    q[(bh * 2048 + ssi) * 64 + hd] = (bf16)(v * 0.180336880111f); // 0.125*log2(e)
                } else if (which == 1) {
                    kk[(bh * 2048 + ssi) * 64 + hd] = (bf16)v;
                } else {
                    vt[(bh * 64 + hd) * 2048 + ssi] = (bf16)v; // V transposed
                }
            }
        }
    }
}

// ---------------- flash attention: S^T formulation, P in registers, nsplit=2 ----------------
__global__ __launch_bounds__(256) void attn_k(const bf16* __restrict__ q,
                                              const bf16* __restrict__ k,
                                              const bf16* __restrict__ vt,
                                              bf16* __restrict__ pO,
                                              float* __restrict__ pL) {
    int bh = blockIdx.y;
    int q0 = blockIdx.x * 128;
    int sz = blockIdx.z;
    const int kt0 = sz * 16;
    int tid = threadIdx.x;
    int lane = tid & 63, w = tid >> 6;
    int quad = lane >> 4, l15 = lane & 15;
    __shared__ bf16 Ks[64 * 72];
    __shared__ bf16 Vs[64 * 72];
    const bf16* qb = q + (size_t)bh * 2048 * 64;
    const bf16* kb = k + (size_t)bh * 2048 * 64;
    const bf16* vb = vt + (size_t)bh * 64 * 2048;
    bf16x8_t qf[2][2]; // B-operand: n=q (l15), k=d (quad*8+j)
#pragma unroll
    for (int qt = 0; qt < 2; ++qt)
#pragma unroll
        for (int ks = 0; ks < 2; ++ks)
            qf[qt][ks] = *(const bf16x8_t*)(qb + (size_t)(q0 + w * 32 + qt * 16 + l15) * 64 + ks * 32 + quad * 8);
    bf16x4_t ones4;
#pragma unroll
    for (int i = 0; i < 4; ++i) ones4[i] = (bf16)1.0f;
    f32x4_t oacc[2][4] = {};
    f32x4_t lacc[2] = {};
    int srow = tid >> 3, ssub = tid & 7;
    uint4 pk[2], pv[2];
    auto gload = [&](int kt) {
        int kbase = kt * 64;
#pragma unroll
        for (int i = 0; i < 2; ++i) {
            int row = i * 32 + srow;
            pk[i] = *(const uint4*)(kb + (size_t)(kbase + row) * 64 + ssub * 8);
            pv[i] = *(const uint4*)(vb + (size_t)row * 2048 + kbase + ssub * 8);
        }
    };
    auto sstore = [&]() {
#pragma unroll
        for (int i = 0; i < 2; ++i) {
            int row = i * 32 + srow;
            *(uint4*)&Ks[row * 72 + ssub * 8] = pk[i];
            *(uint4*)&Vs[row * 72 + ssub * 8] = pv[i];
        }
    };
    gload(kt0);
    for (int kt = kt0; kt < kt0 + 16; ++kt) {
        __syncthreads();
        sstore();
        __syncthreads();
        if (kt + 1 < kt0 + 16) gload(kt + 1); // overlaps with compute below
        // S^T[kv][q] via MFMA(A=K, B=Q); C lane layout {kv=quad*4+r, q=l15} == K=16 A-layout
        f32x4_t sacc[4][2] = {};
#pragma unroll
        for (int ks = 0; ks < 2; ++ks) {
            int koff = ks * 32 + quad * 8;
            bf16x8_t kf[4];
#pragma unroll
            for (int nt = 0; nt < 4; ++nt)
                kf[nt] = *(const bf16x8_t*)&Ks[(nt * 16 + l15) * 72 + koff];
#pragma unroll
            for (int nt = 0; nt < 4; ++nt)
#pragma unroll
                for (int qt = 0; qt < 2; ++qt)
                    sacc[nt][qt] = MFMA16(kf[nt], qf[qt][ks], sacc[nt][qt]);
        }
        bf16x4_t pf[4][2];
#pragma unroll
        for (int nt = 0; nt < 4; ++nt)
#pragma unroll
            for (int qt = 0; qt < 2; ++qt)
#pragma unroll
                for (int r = 0; r < 4; ++r)
                    pf[nt][qt][r] = (bf16)exp2f(sacc[nt][qt][r]);
#pragma unroll
        for (int nt = 0; nt < 4; ++nt) {
            bf16x4_t vf[4];
#pragma unroll
            for (int dt = 0; dt < 4; ++dt)
                vf[dt] = *(const bf16x4_t*)&Vs[(dt * 16 + l15) * 72 + nt * 16 + quad * 4];
#pragma unroll
            for (int qt = 0; qt < 2; ++qt) {
#pragma unroll
                for (int dt = 0; dt < 4; ++dt)
                    oacc[qt][dt] = mfma_k16(pf[nt][qt], vf[dt], oacc[qt][dt]);
                lacc[qt] = mfma_k16(pf[nt][qt], ones4, lacc[qt]);
            }
        }
    }
    size_t obase = ((size_t)(sz * 32 + bh) * 2048 + q0);
#pragma unroll
    for (int qt = 0; qt < 2; ++qt)
#pragma unroll
        for (int r = 0; r < 4; ++r) {
            int row = w * 32 + qt * 16 + quad * 4 + r;
#pragma unroll
            for (int dt = 0; dt < 4; ++dt)
                pO[(obase + row) * 64 + dt * 16 + l15] = (bf16)oacc[qt][dt][r];
            if (l15 == 0) pL[obase + row] = lacc[qt][r];
        }
}

// ---------------- out-proj GEMM with fused split-combine A-staging ----------------
// A[t, k] = (pO0 + pO1)/(l0+l1) at head s = k>>6 (K-slab == head); C = A*wo^T + bout + xn
__global__ __launch_bounds__(256) void gemmo_k(const bf16* __restrict__ pO,
                                               const float* __restrict__ pL,
                                               const bf16* __restrict__ B,
                                               const float* __restrict__ bias,
                                               const bf16* __restrict__ xn,
                                               bf16* __restrict__ xrb,
                                               float* __restrict__ xrf) {
    int m0 = blockIdx.x * 128, n0 = blockIdx.y * 128;
    int tid = threadIdx.x;
    int lane = tid & 63, w = tid >> 6;
    int quad = lane >> 4, l15 = lane & 15;
    int wm = (w >> 1) * 64, wn = (w & 1) * 64;
    __shared__ bf16 As[128 * 72];
    __shared__ bf16 Bs[128 * 72];
    f32x4_t acc[4][4] = {};
    int srow = tid >> 3, ssub = tid & 7;
    const bf16* Bb = B + (size_t)(n0 + srow) * 512 + ssub * 8;
    bf16x8_t pa[4];
    uint4 pb[4];
    auto gload = [&](int s) {
        int k0 = s * 64;
#pragma unroll
        for (int i = 0; i < 4; ++i) {
            int t = m0 + i * 32 + srow;
            int b = t >> 11, ssi = t & 2047;
            size_t r0 = ((size_t)(b * 8 + s)) * 2048 + ssi;      // split 0, head s
            size_t r1 = ((size_t)(32 + b * 8 + s)) * 2048 + ssi; // split 1
            float inv = 1.f / (pL[r0] + pL[r1]);
            bf16x8_t a0 = *(const bf16x8_t*)(pO + r0 * 64 + ssub * 8);
            bf16x8_t a1 = *(const bf16x8_t*)(pO + r1 * 64 + ssub * 8);
            bf16x8_t c;
#pragma unroll
            for (int j = 0; j < 8; ++j) c[j] = (bf16)(((float)a0[j] + (float)a1[j]) * inv);
            pa[i] = c;
            pb[i] = *(const uint4*)(Bb + (size_t)(i * 32) * 512 + k0);
        }
    };
    auto sstore = [&]() {
#pragma unroll
        for (int i = 0; i < 4; ++i) {
            *(bf16x8_t*)&As[(i * 32 + srow) * 72 + ssub * 8] = pa[i];
            *(uint4*)&Bs[(i * 32 + srow) * 72 + ssub * 8] = pb[i];
        }
    };
    gload(0);
    sstore();
    for (int s = 0; s < 8; ++s) {
        __syncthreads();
        if (s < 7) gload(s + 1);
#pragma unroll
        for (int ks = 0; ks < 2; ++ks) {
            bf16x8_t af[4], bfr[4];
            int koff = ks * 32 + quad * 8;
#pragma unroll
            for (int mt = 0; mt < 4; ++mt)
                af[mt] = *(const bf16x8_t*)&As[(wm + mt * 16 + l15) * 72 + koff];
#pragma unroll
            for (int nt = 0; nt < 4; ++nt)
                bfr[nt] = *(const bf16x8_t*)&Bs[(wn + nt * 16 + l15) * 72 + koff];
#pragma unroll
            for (int mt = 0; mt < 4; ++mt)
#pragma unroll
                for (int nt = 0; nt < 4; ++nt)
                    acc[mt][nt] = MFMA16(af[mt], bfr[nt], acc[mt][nt]);
        }
        __syncthreads();
        if (s < 7) sstore();
    }
#pragma unroll
    for (int mt = 0; mt < 4; ++mt) {
#pragma unroll
        for (int nt = 0; nt < 4; ++nt) {
            int gcol = n0 + wn + nt * 16 + l15;
            float bcol = bias[gcol];
#pragma unroll
            for (int r = 0; r < 4; ++r) {
                int grow = m0 + wm + mt * 16 + quad * 4 + r;
                size_t idx = (size_t)grow * 512 + gcol;
                float xv = acc[mt][nt][r] + bcol + (float)xn[idx];
                xrf[idx] = xv;
                xrb[idx] = (bf16)xv;
            }
        }
    }
}

// ---------------- fused MLP gate: h = silu(xr*w1^T+b1); st = sigmoid(h.w2+b2); out = xr*st ----------------
// M-tile 32, full N=256 per block; h never leaves the block.
__global__ __launch_bounds__(256) void mlp_k(const bf16* __restrict__ A,   // xrb [8192,512]
                                             const bf16* __restrict__ B,   // w1b [256,512]
                                             const float* __restrict__ b1,
                                             const float* __restrict__ w2,
                                             const float* __restrict__ b2,
                                             const float* __restrict__ xrf,
                                             float* __restrict__ out) {
    int m0 = blockIdx.x * 32;
    int tid = threadIdx.x;
    int lane = tid & 63, w = tid >> 6;
    int quad = lane >> 4, l15 = lane & 15;
    int wn = w * 64;
    __shared__ bf16 As[32 * 72];
    __shared__ bf16 Bs[256 * 72];
    __shared__ float red[4][32];
    __shared__ float st[32];
    f32x4_t acc[2][4] = {};
    int srow = tid >> 3, ssub = tid & 7;
    uint4 pa, pb[8];
    auto gload = [&](int s) {
        int k0 = s * 64;
        pa = *(const uint4*)(A + (size_t)(m0 + srow) * 512 + ssub * 8 + k0);
#pragma unroll
        for (int i = 0; i < 8; ++i)
            pb[i] = *(const uint4*)(B + (size_t)(i * 32 + srow) * 512 + ssub * 8 + k0);
    };
    auto sstore = [&]() {
        *(uint4*)&As[srow * 72 + ssub * 8] = pa;
#pragma unroll
        for (int i = 0; i < 8; ++i)
            *(uint4*)&Bs[(i * 32 + srow) * 72 + ssub * 8] = pb[i];
    };
    gload(0);
    sstore();
    for (int s = 0; s < 8; ++s) {
        __syncthreads();
        if (s < 7) gload(s + 1);
#pragma unroll
        for (int ks = 0; ks < 2; ++ks) {
            int koff = ks * 32 + quad * 8;
            bf16x8_t af[2], bfr[4];
#pragma unroll
            for (int mt = 0; mt < 2; ++mt)
                af[mt] = *(const bf16x8_t*)&As[(mt * 16 + l15) * 72 + koff];
#pragma unroll
            for (int nt = 0; nt < 4; ++nt)
                bfr[nt] = *(const bf16x8_t*)&Bs[(wn + nt * 16 + l15) * 72 + koff];
#pragma unroll
            for (int mt = 0; mt < 2; ++mt)
#pragma unroll
                for (int nt = 0; nt < 4; ++nt)
                    acc[mt][nt] = MFMA16(af[mt], bfr[nt], acc[mt][nt]);
        }
        __syncthreads();
        if (s < 7) sstore();
    }
    // per-lane partial dot: silu(h)*w2 over this lane's 4 cols, rows quad*4+r (+16*mt)
    f32x4_t ds[2] = {};
#pragma unroll
    for (int mt = 0; mt < 2; ++mt)
#pragma unroll
        for (int nt = 0; nt < 4; ++nt) {
            int gcol = wn + nt * 16 + l15;
            float bb = b1[gcol], ww = w2[gcol];
#pragma unroll
            for (int r = 0; r < 4; ++r) {
                float v = acc[mt][nt][r] + bb;
                float sv = v / (1.f + __expf(-v));
                ds[mt][r] += sv * ww;
            }
        }
#pragma unroll
    for (int m = 1; m < 16; m <<= 1)
#pragma unroll
        for (int mt = 0; mt < 2; ++mt)
#pragma unroll
            for (int r = 0; r < 4; ++r) ds[mt][r] += __shfl_xor(ds[mt][r], m, 64);
    if (l15 == 0) {
#pragma unroll
        for (int mt = 0; mt < 2; ++mt)
#pragma unroll
            for (int r = 0; r < 4; ++r) red[w][mt * 16 + quad * 4 + r] = ds[mt][r];
    }
    __syncthreads();
    if (tid < 32) {
        float d = red[0][tid] + red[1][tid] + red[2][tid] + red[3][tid] + b2[0];
        st[tid] = 1.f / (1.f + __expf(-d));
    }
    __syncthreads();
    // out = xrf * st ; thread: row = tid>>3, 8 lanes sweep 128 float4 per row
    int row = tid >> 3, seg = tid & 7;
    float sr = st[row];
    const float4* x4 = (const float4*)(xrf + (size_t)(m0 + row) * 512);
    float4* o4 = (float4*)(out + (size_t)(m0 + row) * 512);
#pragma unroll
    for (int jj = 0; jj < 16; ++jj) {
        float4 xv = x4[jj * 8 + seg];
        float4 ov;
        ov.x = xv.x * sr; ov.y = xv.y * sr; ov.z = xv.z * sr; ov.w = xv.w * sr;
        o4[jj * 8 + seg] = ov;
    }
}

extern "C" void kernel_launch(void* const* d_in, const int* in_sizes, int n_in,
                              void* d_out, int out_size, void* d_ws, size_t ws_size,
                              hipStream_t stream) {
    const float* x    = (const float*)d_in[0];
    const int*   gt   = (const int*)d_in[1];
    const float* tfg  = (const float*)d_in[2];
    const float* tfb  = (const float*)d_in[3];
    const float* tgg  = (const float*)d_in[4];
    const float* tgb  = (const float*)d_in[5];
    const float* Wqkv = (const float*)d_in[6];
    const float* bqkv = (const float*)d_in[7];
    const float* Wout = (const float*)d_in[8];
    const float* bout = (const float*)d_in[9];
    const float* W1   = (const float*)d_in[10];
    const float* b1   = (const float*)d_in[11];
    const float* w2   = (const float*)d_in[12];
    const float* b2   = (const float*)d_in[13];
    float* out = (float*)d_out;
    char* ws = (char*)d_ws;

    const size_t MB = 1024 * 1024;
    // [0,4MB): weights + row sums
    bf16*  wq  = (bf16*)(ws + 0);                          // 1.5 MB [1536,512]
    bf16*  wo  = (bf16*)(ws + 1536 * 512 * 2);             // 0.5 MB [512,512]
    bf16*  w1b = (bf16*)(ws + (1536 + 512) * 512 * 2);     // 0.25 MB [256,512]
    float* pL  = (float*)(ws + 2304 * 512 * 2);            // 0.5 MB [2][32,2048]
    // activations (aliased by liveness; ws_size >= 70 MB proven in R1)
    bf16*  xn  = (bf16*)(ws + 4 * MB);   //  8 MB [8192,512]          live: castln..gemmo
    bf16*  q   = (bf16*)(ws + 12 * MB);  //  8 MB [32,2048,64]        live: gemmqkv..attn
    bf16*  xrb = (bf16*)(ws + 12 * MB);  //  8 MB [8192,512] (=q)     live: gemmo..mlp
    bf16*  kk  = (bf16*)(ws + 20 * MB);  //  8 MB [32,2048,64]        live: gemmqkv..attn
    bf16*  vt  = (bf16*)(ws + 28 * MB);  //  8 MB [32,64,2048]        live: gemmqkv..attn
    bf16*  pO  = (bf16*)(ws + 36 * MB);  // 16 MB [2][32,2048,64]     live: attn..gemmo
    float* xrf = (float*)(ws + 52 * MB); // 16 MB [8192,512]          live: gemmo..mlp

    castln_k<<<6656, 256, 0, stream>>>(Wqkv, Wout, W1, wq, wo, w1b,
                                       x, gt, tfg, tfb, tgg, tgb, xn);
    gemmqkv_k<<<dim3(64, 12), 256, 0, stream>>>(xn, wq, bqkv, q, kk, vt);
    attn_k<<<dim3(16, 32, 2), 256, 0, stream>>>(q, kk, vt, pO, pL);
    gemmo_k<<<dim3(64, 4), 256, 0, stream>>>(pO, pL, wo, bout, xn, xrb, xrf);
    mlp_k<<<256, 256, 0, stream>>>(xrb, w1b, b1, w2, b2, xrf, out);
    (void)in_sizes; (void)n_in; (void)out_size; (void)ws_size;
}

// Round 6
// 331.674 us; speedup vs baseline: 1.0403x; 1.0135x over previous
//
#include <hip/hip_runtime.h>

typedef __bf16 bf16;
typedef __bf16 bf16x4_t __attribute__((ext_vector_type(4)));
typedef __bf16 bf16x8_t __attribute__((ext_vector_type(8)));
typedef float f32x4_t __attribute__((ext_vector_type(4)));

#define MFMA16(a, b, c) __builtin_amdgcn_mfma_f32_16x16x32_bf16(a, b, c, 0, 0, 0)

// ---------------- fused: weight casts (blocks 0..4607) + conditional LN (4608..6655) ----------------
__global__ __launch_bounds__(256) void castln_k(const float* __restrict__ Wqkv,
                                                const float* __restrict__ Wout,
                                                const float* __restrict__ W1,
                                                bf16* __restrict__ wq,
                                                bf16* __restrict__ wo,
                                                bf16* __restrict__ w1b,
                                                const float* __restrict__ x,
                                                const int* __restrict__ gt,
                                                const float* __restrict__ tfg,
                                                const float* __restrict__ tfb,
                                                const float* __restrict__ tgg,
                                                const float* __restrict__ tgb,
                                                bf16* __restrict__ xn) {
    if (blockIdx.x < 4608) {
        int i = blockIdx.x * 256 + threadIdx.x;
        if (i < 786432) wq[i] = (bf16)Wqkv[i];
        else if (i < 1048576) wo[i - 786432] = (bf16)Wout[i - 786432];
        else if (i < 1179648) w1b[i - 1048576] = (bf16)W1[i - 1048576];
        return;
    }
    int wid = threadIdx.x >> 6, lane = threadIdx.x & 63;
    int t = (blockIdx.x - 4608) * 4 + wid;
    const float4* xr = (const float4*)(x + (size_t)t * 512);
    float4 a = xr[lane * 2], b = xr[lane * 2 + 1];
    float s = (a.x + a.y) + (a.z + a.w) + (b.x + b.y) + (b.z + b.w);
    float sq = a.x * a.x + a.y * a.y + a.z * a.z + a.w * a.w +
               b.x * b.x + b.y * b.y + b.z * b.z + b.w * b.w;
    for (int m = 1; m < 64; m <<= 1) {
        s += __shfl_xor(s, m, 64);
        sq += __shfl_xor(sq, m, 64);
    }
    float mean = s * (1.f / 512.f);
    float var = fmaxf(sq * (1.f / 512.f) - mean * mean, 0.f);
    float rstd = rsqrtf(var + 1e-5f);
    int g = gt[t];
    float4 o0, o1;
    if (g < 2) {
        const float4* gp = (const float4*)(g ? tgg : tfg);
        const float4* bp = (const float4*)(g ? tgb : tfb);
        float4 g0 = gp[lane * 2], g1 = gp[lane * 2 + 1];
        float4 b0 = bp[lane * 2], b1 = bp[lane * 2 + 1];
        o0.x = (a.x - mean) * rstd * g0.x + b0.x;
        o0.y = (a.y - mean) * rstd * g0.y + b0.y;
        o0.z = (a.z - mean) * rstd * g0.z + b0.z;
        o0.w = (a.w - mean) * rstd * g0.w + b0.w;
        o1.x = (b.x - mean) * rstd * g1.x + b1.x;
        o1.y = (b.y - mean) * rstd * g1.y + b1.y;
        o1.z = (b.z - mean) * rstd * g1.z + b1.z;
        o1.w = (b.w - mean) * rstd * g1.w + b1.w;
    } else {
        o0 = a; o1 = b;
    }
    bf16* xo = xn + (size_t)t * 512 + lane * 8;
    bf16x4_t p0, p1;
    p0[0] = (bf16)o0.x; p0[1] = (bf16)o0.y; p0[2] = (bf16)o0.z; p0[3] = (bf16)o0.w;
    p1[0] = (bf16)o1.x; p1[1] = (bf16)o1.y; p1[2] = (bf16)o1.z; p1[3] = (bf16)o1.w;
    *(bf16x4_t*)xo = p0;
    *(bf16x4_t*)(xo + 4) = p1;
}

// ---------------- QKV GEMM: C[M,1536] = xn * Wqkv^T; q/k/v all written [BH,S,64] coalesced ----------------
__global__ __launch_bounds__(256) void gemmqkv_k(const bf16* __restrict__ A,
                                                 const bf16* __restrict__ B,
                                                 const float* __restrict__ bias,
                                                 bf16* __restrict__ q,
                                                 bf16* __restrict__ kk,
                                                 bf16* __restrict__ vv) {
    int m0 = blockIdx.x * 128, n0 = blockIdx.y * 128;
    int tid = threadIdx.x;
    int lane = tid & 63, w = tid >> 6;
    int quad = lane >> 4, l15 = lane & 15;
    int wm = (w >> 1) * 64, wn = (w & 1) * 64;
    __shared__ bf16 As[128 * 72];
    __shared__ bf16 Bs[128 * 72];
    f32x4_t acc[4][4] = {};
    int srow = tid >> 3, ssub = tid & 7;
    const bf16* Ab = A + (size_t)(m0 + srow) * 512 + ssub * 8;
    const bf16* Bb = B + (size_t)(n0 + srow) * 512 + ssub * 8;
    uint4 pa[4], pb[4];
    auto gload = [&](int s) {
        int k0 = s * 64;
#pragma unroll
        for (int i = 0; i < 4; ++i) {
            pa[i] = *(const uint4*)(Ab + (size_t)(i * 32) * 512 + k0);
            pb[i] = *(const uint4*)(Bb + (size_t)(i * 32) * 512 + k0);
        }
    };
    auto sstore = [&]() {
#pragma unroll
        for (int i = 0; i < 4; ++i) {
            *(uint4*)&As[(i * 32 + srow) * 72 + ssub * 8] = pa[i];
            *(uint4*)&Bs[(i * 32 + srow) * 72 + ssub * 8] = pb[i];
        }
    };
    gload(0);
    sstore();
    for (int s = 0; s < 8; ++s) {
        __syncthreads();
        if (s < 7) gload(s + 1);
#pragma unroll
        for (int ks = 0; ks < 2; ++ks) {
            bf16x8_t af[4], bfr[4];
            int koff = ks * 32 + quad * 8;
#pragma unroll
            for (int mt = 0; mt < 4; ++mt)
                af[mt] = *(const bf16x8_t*)&As[(wm + mt * 16 + l15) * 72 + koff];
#pragma unroll
            for (int nt = 0; nt < 4; ++nt)
                bfr[nt] = *(const bf16x8_t*)&Bs[(wn + nt * 16 + l15) * 72 + koff];
#pragma unroll
            for (int mt = 0; mt < 4; ++mt)
#pragma unroll
                for (int nt = 0; nt < 4; ++nt)
                    acc[mt][nt] = MFMA16(af[mt], bfr[nt], acc[mt][nt]);
        }
        __syncthreads();
        if (s < 7) sstore();
    }
#pragma unroll
    for (int mt = 0; mt < 4; ++mt) {
#pragma unroll
        for (int nt = 0; nt < 4; ++nt) {
            int gcol = n0 + wn + nt * 16 + l15;
            float bcol = bias[gcol];
#pragma unroll
            for (int r = 0; r < 4; ++r) {
                int grow = m0 + wm + mt * 16 + quad * 4 + r;
                float v = acc[mt][nt][r] + bcol;
                int which = gcol >> 9;
                int d = gcol & 511;
                int hh = d >> 6, hd = d & 63;
                int b = grow >> 11, ssi = grow & 2047;
                size_t bh = (size_t)(b * 8 + hh);
                size_t idx = (bh * 2048 + ssi) * 64 + hd;
                if (which == 0) {
                    q[idx] = (bf16)(v * 0.180336880111f); // 0.125*log2(e)
                } else if (which == 1) {
                    kk[idx] = (bf16)v;
                } else {
                    vv[idx] = (bf16)v; // coalesced; transpose happens in vtrans_k
                }
            }
        }
    }
}

// ---------------- V transpose: [BH,S,64] -> [BH,64,S], LDS-tiled, coalesced both ways ----------------
__global__ __launch_bounds__(256) void vtrans_k(const bf16* __restrict__ v,
                                                bf16* __restrict__ vt) {
    int bh = blockIdx.y;
    int s0 = blockIdx.x * 64;
    __shared__ bf16 Ls[64][72];
    int tid = threadIdx.x;
    int row = tid >> 2, seg = tid & 3;
    const bf16* vb = v + ((size_t)bh * 2048 + s0 + row) * 64 + seg * 16;
    *(uint4*)&Ls[row][seg * 16] = *(const uint4*)vb;
    *(uint4*)&Ls[row][seg * 16 + 8] = *(const uint4*)(vb + 8);
    __syncthreads();
    // thread writes d=row, s in [seg*16, seg*16+16)
    bf16 tmp[16];
#pragma unroll
    for (int i = 0; i < 16; ++i) tmp[i] = Ls[seg * 16 + i][row];
    bf16* dst = vt + ((size_t)bh * 64 + row) * 2048 + s0 + seg * 16;
    *(uint4*)dst = *(uint4*)&tmp[0];
    *(uint4*)(dst + 8) = *(uint4*)&tmp[8];
}

// ---------------- flash attention: LDS-P (all MFMAs K=32), pipelined staging, nsplit=2 ----------------
// q,k: [BH,S,64] (q pre-scaled by 0.125*log2e); vt: [BH,64,S]
// pO: [2][BH,S,64] bf16 un-normalized; pL: [2][BH,S] f32 row sums
__global__ __launch_bounds__(256) void attn_k(const bf16* __restrict__ q,
                                              const bf16* __restrict__ k,
                                              const bf16* __restrict__ vt,
                                              bf16* __restrict__ pO,
                                              float* __restrict__ pL) {
    int bh = blockIdx.y;
    int q0 = blockIdx.x * 128;
    int sz = blockIdx.z;
    int kt0 = sz * 16;
    int tid = threadIdx.x;
    int lane = tid & 63, w = tid >> 6;
    int quad = lane >> 4, l15 = lane & 15;
    __shared__ bf16 Ks[64 * 72];
    __shared__ bf16 Vs[64 * 72];
    __shared__ bf16 Ps[128 * 72];
    const bf16* qb = q + (size_t)bh * 2048 * 64;
    const bf16* kb = k + (size_t)bh * 2048 * 64;
    const bf16* vb = vt + (size_t)bh * 64 * 2048;
    bf16x8_t qf[2][2]; // A-operand: m=q (l15), k=d (quad*8+j)
#pragma unroll
    for (int mt = 0; mt < 2; ++mt)
#pragma unroll
        for (int ks = 0; ks < 2; ++ks)
            qf[mt][ks] = *(const bf16x8_t*)(qb + (size_t)(q0 + w * 32 + mt * 16 + l15) * 64 + ks * 32 + quad * 8);
    bf16x8_t ones8;
#pragma unroll
    for (int i = 0; i < 8; ++i) ones8[i] = (bf16)1.0f;
    f32x4_t oacc[2][4] = {};
    f32x4_t lacc[2] = {};
    int srow = tid >> 3, ssub = tid & 7;
    uint4 pk[2], pw[2];
    auto gload = [&](int kt) {
        int kbase = kt * 64;
#pragma unroll
        for (int i = 0; i < 2; ++i) {
            int row = i * 32 + srow;
            pk[i] = *(const uint4*)(kb + (size_t)(kbase + row) * 64 + ssub * 8);
            pw[i] = *(const uint4*)(vb + (size_t)row * 2048 + kbase + ssub * 8);
        }
    };
    auto sstore = [&]() {
#pragma unroll
        for (int i = 0; i < 2; ++i) {
            int row = i * 32 + srow;
            *(uint4*)&Ks[row * 72 + ssub * 8] = pk[i];
            *(uint4*)&Vs[row * 72 + ssub * 8] = pw[i];
        }
    };
    gload(kt0);
    for (int kt = kt0; kt < kt0 + 16; ++kt) {
        __syncthreads(); // prev tile's LDS readers done
        sstore();
        __syncthreads();
        if (kt + 1 < kt0 + 16) gload(kt + 1); // overlaps compute below
        // S = Q K^T : C row=q(quad*4+r), col=kv(l15)
        f32x4_t sacc[2][4] = {};
#pragma unroll
        for (int ks = 0; ks < 2; ++ks) {
            int koff = ks * 32 + quad * 8;
            bf16x8_t kf[4];
#pragma unroll
            for (int nt = 0; nt < 4; ++nt)
                kf[nt] = *(const bf16x8_t*)&Ks[(nt * 16 + l15) * 72 + koff];
#pragma unroll
            for (int mt = 0; mt < 2; ++mt)
#pragma unroll
                for (int nt = 0; nt < 4; ++nt)
                    sacc[mt][nt] = MFMA16(qf[mt][ks], kf[nt], sacc[mt][nt]);
        }
        // P = exp2(S) -> Ps[q][kv] (wave-private rows, no barrier)
#pragma unroll
        for (int mt = 0; mt < 2; ++mt)
#pragma unroll
            for (int nt = 0; nt < 4; ++nt)
#pragma unroll
                for (int r = 0; r < 4; ++r)
                    Ps[(w * 32 + mt * 16 + quad * 4 + r) * 72 + nt * 16 + l15] = (bf16)exp2f(sacc[mt][nt][r]);
        // O += P V ; l += P . 1 (all K=32 MFMAs)
#pragma unroll
        for (int ks = 0; ks < 2; ++ks) {
            int koff = ks * 32 + quad * 8;
            bf16x8_t pf[2], vf[4];
#pragma unroll
            for (int mt = 0; mt < 2; ++mt)
                pf[mt] = *(const bf16x8_t*)&Ps[(w * 32 + mt * 16 + l15) * 72 + koff];
#pragma unroll
            for (int nt = 0; nt < 4; ++nt)
                vf[nt] = *(const bf16x8_t*)&Vs[(nt * 16 + l15) * 72 + koff];
#pragma unroll
            for (int mt = 0; mt < 2; ++mt) {
#pragma unroll
                for (int nt = 0; nt < 4; ++nt)
                    oacc[mt][nt] = MFMA16(pf[mt], vf[nt], oacc[mt][nt]);
                lacc[mt] = MFMA16(pf[mt], ones8, lacc[mt]);
            }
        }
    }
    size_t obase = ((size_t)(sz * 32 + bh) * 2048 + q0);
#pragma unroll
    for (int mt = 0; mt < 2; ++mt)
#pragma unroll
        for (int r = 0; r < 4; ++r) {
            int row = w * 32 + mt * 16 + quad * 4 + r;
#pragma unroll
            for (int nt = 0; nt < 4; ++nt)
                pO[(obase + row) * 64 + nt * 16 + l15] = (bf16)oacc[mt][nt][r];
            if (l15 == 0) pL[obase + row] = lacc[mt][r];
        }
}

// ---------------- out-proj GEMM with fused split-combine A-staging ----------------
// A[t, k] = (pO0 + pO1)/(l0+l1) at head s = k>>6 (K-slab == head); C = A*wo^T + bout + xn
__global__ __launch_bounds__(256) void gemmo_k(const bf16* __restrict__ pO,
                                               const float* __restrict__ pL,
                                               const bf16* __restrict__ B,
                                               const float* __restrict__ bias,
                                               const bf16* __restrict__ xn,
                                               bf16* __restrict__ xrb,
                                               float* __restrict__ xrf) {
    int m0 = blockIdx.x * 128, n0 = blockIdx.y * 128;
    int tid = threadIdx.x;
    int lane = tid & 63, w = tid >> 6;
    int quad = lane >> 4, l15 = lane & 15;
    int wm = (w >> 1) * 64, wn = (w & 1) * 64;
    __shared__ bf16 As[128 * 72];
    __shared__ bf16 Bs[128 * 72];
    f32x4_t acc[4][4] = {};
    int srow = tid >> 3, ssub = tid & 7;
    const bf16* Bb = B + (size_t)(n0 + srow) * 512 + ssub * 8;
    bf16x8_t pa[4];
    uint4 pb[4];
    auto gload = [&](int s) {
        int k0 = s * 64;
#pragma unroll
        for (int i = 0; i < 4; ++i) {
            int t = m0 + i * 32 + srow;
            int b = t >> 11, ssi = t & 2047;
            size_t r0 = ((size_t)(b * 8 + s)) * 2048 + ssi;      // split 0, head s
            size_t r1 = ((size_t)(32 + b * 8 + s)) * 2048 + ssi; // split 1
            float inv = 1.f / (pL[r0] + pL[r1]);
            bf16x8_t a0 = *(const bf16x8_t*)(pO + r0 * 64 + ssub * 8);
            bf16x8_t a1 = *(const bf16x8_t*)(pO + r1 * 64 + ssub * 8);
            bf16x8_t c;
#pragma unroll
            for (int j = 0; j < 8; ++j) c[j] = (bf16)(((float)a0[j] + (float)a1[j]) * inv);
            pa[i] = c;
            pb[i] = *(const uint4*)(Bb + (size_t)(i * 32) * 512 + k0);
        }
    };
    auto sstore = [&]() {
#pragma unroll
        for (int i = 0; i < 4; ++i) {
            *(bf16x8_t*)&As[(i * 32 + srow) * 72 + ssub * 8] = pa[i];
            *(uint4*)&Bs[(i * 32 + srow) * 72 + ssub * 8] = pb[i];
        }
    };
    gload(0);
    sstore();
    for (int s = 0; s < 8; ++s) {
        __syncthreads();
        if (s < 7) gload(s + 1);
#pragma unroll
        for (int ks = 0; ks < 2; ++ks) {
            bf16x8_t af[4], bfr[4];
            int koff = ks * 32 + quad * 8;
#pragma unroll
            for (int mt = 0; mt < 4; ++mt)
                af[mt] = *(const bf16x8_t*)&As[(wm + mt * 16 + l15) * 72 + koff];
#pragma unroll
            for (int nt = 0; nt < 4; ++nt)
                bfr[nt] = *(const bf16x8_t*)&Bs[(wn + nt * 16 + l15) * 72 + koff];
#pragma unroll
            for (int mt = 0; mt < 4; ++mt)
#pragma unroll
                for (int nt = 0; nt < 4; ++nt)
                    acc[mt][nt] = MFMA16(af[mt], bfr[nt], acc[mt][nt]);
        }
        __syncthreads();
        if (s < 7) sstore();
    }
#pragma unroll
    for (int mt = 0; mt < 4; ++mt) {
#pragma unroll
        for (int nt = 0; nt < 4; ++nt) {
            int gcol = n0 + wn + nt * 16 + l15;
            float bcol = bias[gcol];
#pragma unroll
            for (int r = 0; r < 4; ++r) {
                int grow = m0 + wm + mt * 16 + quad * 4 + r;
                size_t idx = (size_t)grow * 512 + gcol;
                float xv = acc[mt][nt][r] + bcol + (float)xn[idx];
                xrf[idx] = xv;
                xrb[idx] = (bf16)xv;
            }
        }
    }
}

// ---------------- fused MLP gate: h = silu(xr*w1^T+b1); st = sigmoid(h.w2+b2); out = xr*st ----------------
__global__ __launch_bounds__(256) void mlp_k(const bf16* __restrict__ A,   // xrb [8192,512]
                                             const bf16* __restrict__ B,   // w1b [256,512]
                                             const float* __restrict__ b1,
                                             const float* __restrict__ w2,
                                             const float* __restrict__ b2,
                                             const float* __restrict__ xrf,
                                             float* __restrict__ out) {
    int m0 = blockIdx.x * 32;
    int tid = threadIdx.x;
    int lane = tid & 63, w = tid >> 6;
    int quad = lane >> 4, l15 = lane & 15;
    int wn = w * 64;
    __shared__ bf16 As[32 * 72];
    __shared__ bf16 Bs[256 * 72];
    __shared__ float red[4][32];
    __shared__ float st[32];
    f32x4_t acc[2][4] = {};
    int srow = tid >> 3, ssub = tid & 7;
    uint4 pa, pb[8];
    auto gload = [&](int s) {
        int k0 = s * 64;
        pa = *(const uint4*)(A + (size_t)(m0 + srow) * 512 + ssub * 8 + k0);
#pragma unroll
        for (int i = 0; i < 8; ++i)
            pb[i] = *(const uint4*)(B + (size_t)(i * 32 + srow) * 512 + ssub * 8 + k0);
    };
    auto sstore = [&]() {
        *(uint4*)&As[srow * 72 + ssub * 8] = pa;
#pragma unroll
        for (int i = 0; i < 8; ++i)
            *(uint4*)&Bs[(i * 32 + srow) * 72 + ssub * 8] = pb[i];
    };
    gload(0);
    sstore();
    for (int s = 0; s < 8; ++s) {
        __syncthreads();
        if (s < 7) gload(s + 1);
#pragma unroll
        for (int ks = 0; ks < 2; ++ks) {
            int koff = ks * 32 + quad * 8;
            bf16x8_t af[2], bfr[4];
#pragma unroll
            for (int mt = 0; mt < 2; ++mt)
                af[mt] = *(const bf16x8_t*)&As[(mt * 16 + l15) * 72 + koff];
#pragma unroll
            for (int nt = 0; nt < 4; ++nt)
                bfr[nt] = *(const bf16x8_t*)&Bs[(wn + nt * 16 + l15) * 72 + koff];
#pragma unroll
            for (int mt = 0; mt < 2; ++mt)
#pragma unroll
                for (int nt = 0; nt < 4; ++nt)
                    acc[mt][nt] = MFMA16(af[mt], bfr[nt], acc[mt][nt]);
        }
        __syncthreads();
        if (s < 7) sstore();
    }
    f32x4_t ds[2] = {};
#pragma unroll
    for (int mt = 0; mt < 2; ++mt)
#pragma unroll
        for (int nt = 0; nt < 4; ++nt) {
            int gcol = wn + nt * 16 + l15;
            float bb = b1[gcol], ww = w2[gcol];
#pragma unroll
            for (int r = 0; r < 4; ++r) {
                float v = acc[mt][nt][r] + bb;
                float sv = v / (1.f + __expf(-v));
                ds[mt][r] += sv * ww;
            }
        }
#pragma unroll
    for (int m = 1; m < 16; m <<= 1)
#pragma unroll
        for (int mt = 0; mt < 2; ++mt)
#pragma unroll
            for (int r = 0; r < 4; ++r) ds[mt][r] += __shfl_xor(ds[mt][r], m, 64);
    if (l15 == 0) {
#pragma unroll
        for (int mt = 0; mt < 2; ++mt)
#pragma unroll
            for (int r = 0; r < 4; ++r) red[w][mt * 16 + quad * 4 + r] = ds[mt][r];
    }
    __syncthreads();
    if (tid < 32) {
        float d = red[0][tid] + red[1][tid] + red[2][tid] + red[3][tid] + b2[0];
        st[tid] = 1.f / (1.f + __expf(-d));
    }
    __syncthreads();
    int row = tid >> 3, seg = tid & 7;
    float sr = st[row];
    const float4* x4 = (const float4*)(xrf + (size_t)(m0 + row) * 512);
    float4* o4 = (float4*)(out + (size_t)(m0 + row) * 512);
#pragma unroll
    for (int jj = 0; jj < 16; ++jj) {
        float4 xv = x4[jj * 8 + seg];
        float4 ov;
        ov.x = xv.x * sr; ov.y = xv.y * sr; ov.z = xv.z * sr; ov.w = xv.w * sr;
        o4[jj * 8 + seg] = ov;
    }
}

extern "C" void kernel_launch(void* const* d_in, const int* in_sizes, int n_in,
                              void* d_out, int out_size, void* d_ws, size_t ws_size,
                              hipStream_t stream) {
    const float* x    = (const float*)d_in[0];
    const int*   gt   = (const int*)d_in[1];
    const float* tfg  = (const float*)d_in[2];
    const float* tfb  = (const float*)d_in[3];
    const float* tgg  = (const float*)d_in[4];
    const float* tgb  = (const float*)d_in[5];
    const float* Wqkv = (const float*)d_in[6];
    const float* bqkv = (const float*)d_in[7];
    const float* Wout = (const float*)d_in[8];
    const float* bout = (const float*)d_in[9];
    const float* W1   = (const float*)d_in[10];
    const float* b1   = (const float*)d_in[11];
    const float* w2   = (const float*)d_in[12];
    const float* b2   = (const float*)d_in[13];
    float* out = (float*)d_out;
    char* ws = (char*)d_ws;

    const size_t MB = 1024 * 1024;
    // [0,4MB): weights + row sums
    bf16*  wq  = (bf16*)(ws + 0);                          // 1.5 MB [1536,512]
    bf16*  wo  = (bf16*)(ws + 1536 * 512 * 2);             // 0.5 MB [512,512]
    bf16*  w1b = (bf16*)(ws + (1536 + 512) * 512 * 2);     // 0.25 MB [256,512]
    float* pL  = (float*)(ws + 2304 * 512 * 2);            // 0.5 MB [2][32,2048]
    // activations (aliased by liveness); peak 60 MB (ws_size >= ~74 MB proven in R1)
    bf16*  xn  = (bf16*)(ws + 4 * MB);   //  8 MB [8192,512]          live: castln..gemmo
    bf16*  q   = (bf16*)(ws + 12 * MB);  //  8 MB [32,2048,64]        live: gemmqkv..attn
    bf16*  xrb = (bf16*)(ws + 12 * MB);  //  8 MB [8192,512] (=q)     live: gemmo..mlp
    bf16*  kk  = (bf16*)(ws + 20 * MB);  //  8 MB [32,2048,64]        live: gemmqkv..attn
    bf16*  vv  = (bf16*)(ws + 28 * MB);  //  8 MB [32,2048,64]        live: gemmqkv..vtrans
    bf16*  vt  = (bf16*)(ws + 36 * MB);  //  8 MB [32,64,2048]        live: vtrans..attn
    float* xrf = (float*)(ws + 28 * MB); // 16 MB [8192,512] (=vv,vt) live: gemmo..mlp
    bf16*  pO  = (bf16*)(ws + 44 * MB);  // 16 MB [2][32,2048,64]     live: attn..gemmo

    castln_k<<<6656, 256, 0, stream>>>(Wqkv, Wout, W1, wq, wo, w1b,
                                       x, gt, tfg, tfb, tgg, tgb, xn);
    gemmqkv_k<<<dim3(64, 12), 256, 0, stream>>>(xn, wq, bqkv, q, kk, vv);
    vtrans_k<<<dim3(32, 32), 256, 0, stream>>>(vv, vt);
    attn_k<<<dim3(16, 32, 2), 256, 0, stream>>>(q, kk, vt, pO, pL);
    gemmo_k<<<dim3(64, 4), 256, 0, stream>>>(pO, pL, wo, bout, xn, xrb, xrf);
    mlp_k<<<256, 256, 0, stream>>>(xrb, w1b, b1, w2, b2, xrf, out);
    (void)in_sizes; (void)n_in; (void)out_size; (void)ws_size;
}

// Round 7
// 330.551 us; speedup vs baseline: 1.0438x; 1.0034x over previous
//
#include <hip/hip_runtime.h>

typedef __bf16 bf16;
typedef __bf16 bf16x4_t __attribute__((ext_vector_type(4)));
typedef __bf16 bf16x8_t __attribute__((ext_vector_type(8)));
typedef float f32x4_t __attribute__((ext_vector_type(4)));

#define MFMA16(a, b, c) __builtin_amdgcn_mfma_f32_16x16x32_bf16(a, b, c, 0, 0, 0)

// ---------------- fused: weight casts (blocks 0..4607) + conditional LN (4608..6655) ----------------
__global__ __launch_bounds__(256) void castln_k(const float* __restrict__ Wqkv,
                                                const float* __restrict__ Wout,
                                                const float* __restrict__ W1,
                                                bf16* __restrict__ wq,
                                                bf16* __restrict__ wo,
                                                bf16* __restrict__ w1b,
                                                const float* __restrict__ x,
                                                const int* __restrict__ gt,
                                                const float* __restrict__ tfg,
                                                const float* __restrict__ tfb,
                                                const float* __restrict__ tgg,
                                                const float* __restrict__ tgb,
                                                bf16* __restrict__ xn) {
    if (blockIdx.x < 4608) {
        int i = blockIdx.x * 256 + threadIdx.x;
        if (i < 786432) wq[i] = (bf16)Wqkv[i];
        else if (i < 1048576) wo[i - 786432] = (bf16)Wout[i - 786432];
        else if (i < 1179648) w1b[i - 1048576] = (bf16)W1[i - 1048576];
        return;
    }
    int wid = threadIdx.x >> 6, lane = threadIdx.x & 63;
    int t = (blockIdx.x - 4608) * 4 + wid;
    const float4* xr = (const float4*)(x + (size_t)t * 512);
    float4 a = xr[lane * 2], b = xr[lane * 2 + 1];
    float s = (a.x + a.y) + (a.z + a.w) + (b.x + b.y) + (b.z + b.w);
    float sq = a.x * a.x + a.y * a.y + a.z * a.z + a.w * a.w +
               b.x * b.x + b.y * b.y + b.z * b.z + b.w * b.w;
    for (int m = 1; m < 64; m <<= 1) {
        s += __shfl_xor(s, m, 64);
        sq += __shfl_xor(sq, m, 64);
    }
    float mean = s * (1.f / 512.f);
    float var = fmaxf(sq * (1.f / 512.f) - mean * mean, 0.f);
    float rstd = rsqrtf(var + 1e-5f);
    int g = gt[t];
    float4 o0, o1;
    if (g < 2) {
        const float4* gp = (const float4*)(g ? tgg : tfg);
        const float4* bp = (const float4*)(g ? tgb : tfb);
        float4 g0 = gp[lane * 2], g1 = gp[lane * 2 + 1];
        float4 b0 = bp[lane * 2], b1 = bp[lane * 2 + 1];
        o0.x = (a.x - mean) * rstd * g0.x + b0.x;
        o0.y = (a.y - mean) * rstd * g0.y + b0.y;
        o0.z = (a.z - mean) * rstd * g0.z + b0.z;
        o0.w = (a.w - mean) * rstd * g0.w + b0.w;
        o1.x = (b.x - mean) * rstd * g1.x + b1.x;
        o1.y = (b.y - mean) * rstd * g1.y + b1.y;
        o1.z = (b.z - mean) * rstd * g1.z + b1.z;
        o1.w = (b.w - mean) * rstd * g1.w + b1.w;
    } else {
        o0 = a; o1 = b;
    }
    bf16* xo = xn + (size_t)t * 512 + lane * 8;
    bf16x4_t p0, p1;
    p0[0] = (bf16)o0.x; p0[1] = (bf16)o0.y; p0[2] = (bf16)o0.z; p0[3] = (bf16)o0.w;
    p1[0] = (bf16)o1.x; p1[1] = (bf16)o1.y; p1[2] = (bf16)o1.z; p1[3] = (bf16)o1.w;
    *(bf16x4_t*)xo = p0;
    *(bf16x4_t*)(xo + 4) = p1;
}

// ---------------- QKV GEMM: C[M,1536] = xn * Wqkv^T; q/k/v all written [BH,S,64] coalesced ----------------
__global__ __launch_bounds__(256) void gemmqkv_k(const bf16* __restrict__ A,
                                                 const bf16* __restrict__ B,
                                                 const float* __restrict__ bias,
                                                 bf16* __restrict__ q,
                                                 bf16* __restrict__ kk,
                                                 bf16* __restrict__ vv) {
    int m0 = blockIdx.x * 128, n0 = blockIdx.y * 128;
    int tid = threadIdx.x;
    int lane = tid & 63, w = tid >> 6;
    int quad = lane >> 4, l15 = lane & 15;
    int wm = (w >> 1) * 64, wn = (w & 1) * 64;
    __shared__ bf16 As[128 * 72];
    __shared__ bf16 Bs[128 * 72];
    f32x4_t acc[4][4] = {};
    int srow = tid >> 3, ssub = tid & 7;
    const bf16* Ab = A + (size_t)(m0 + srow) * 512 + ssub * 8;
    const bf16* Bb = B + (size_t)(n0 + srow) * 512 + ssub * 8;
    uint4 pa[4], pb[4];
    auto gload = [&](int s) {
        int k0 = s * 64;
#pragma unroll
        for (int i = 0; i < 4; ++i) {
            pa[i] = *(const uint4*)(Ab + (size_t)(i * 32) * 512 + k0);
            pb[i] = *(const uint4*)(Bb + (size_t)(i * 32) * 512 + k0);
        }
    };
    auto sstore = [&]() {
#pragma unroll
        for (int i = 0; i < 4; ++i) {
            *(uint4*)&As[(i * 32 + srow) * 72 + ssub * 8] = pa[i];
            *(uint4*)&Bs[(i * 32 + srow) * 72 + ssub * 8] = pb[i];
        }
    };
    gload(0);
    sstore();
    for (int s = 0; s < 8; ++s) {
        __syncthreads();
        if (s < 7) gload(s + 1);
#pragma unroll
        for (int ks = 0; ks < 2; ++ks) {
            bf16x8_t af[4], bfr[4];
            int koff = ks * 32 + quad * 8;
#pragma unroll
            for (int mt = 0; mt < 4; ++mt)
                af[mt] = *(const bf16x8_t*)&As[(wm + mt * 16 + l15) * 72 + koff];
#pragma unroll
            for (int nt = 0; nt < 4; ++nt)
                bfr[nt] = *(const bf16x8_t*)&Bs[(wn + nt * 16 + l15) * 72 + koff];
#pragma unroll
            for (int mt = 0; mt < 4; ++mt)
#pragma unroll
                for (int nt = 0; nt < 4; ++nt)
                    acc[mt][nt] = MFMA16(af[mt], bfr[nt], acc[mt][nt]);
        }
        __syncthreads();
        if (s < 7) sstore();
    }
#pragma unroll
    for (int mt = 0; mt < 4; ++mt) {
#pragma unroll
        for (int nt = 0; nt < 4; ++nt) {
            int gcol = n0 + wn + nt * 16 + l15;
            float bcol = bias[gcol];
#pragma unroll
            for (int r = 0; r < 4; ++r) {
                int grow = m0 + wm + mt * 16 + quad * 4 + r;
                float v = acc[mt][nt][r] + bcol;
                int which = gcol >> 9;
                int d = gcol & 511;
                int hh = d >> 6, hd = d & 63;
                int b = grow >> 11, ssi = grow & 2047;
                size_t bh = (size_t)(b * 8 + hh);
                size_t idx = (bh * 2048 + ssi) * 64 + hd;
                if (which == 0) {
                    q[idx] = (bf16)(v * 0.180336880111f); // 0.125*log2(e)
                } else if (which == 1) {
                    kk[idx] = (bf16)v;
                } else {
                    vv[idx] = (bf16)v; // coalesced; transpose happens in vtrans_k
                }
            }
        }
    }
}

// ---------------- V transpose: [BH,S,64] -> [BH,64,S], LDS-tiled, coalesced both ways ----------------
__global__ __launch_bounds__(256) void vtrans_k(const bf16* __restrict__ v,
                                                bf16* __restrict__ vt) {
    int bh = blockIdx.y;
    int s0 = blockIdx.x * 64;
    __shared__ bf16 Ls[64][72];
    int tid = threadIdx.x;
    int row = tid >> 2, seg = tid & 3;
    const bf16* vb = v + ((size_t)bh * 2048 + s0 + row) * 64 + seg * 16;
    *(uint4*)&Ls[row][seg * 16] = *(const uint4*)vb;
    *(uint4*)&Ls[row][seg * 16 + 8] = *(const uint4*)(vb + 8);
    __syncthreads();
    bf16 tmp[16];
#pragma unroll
    for (int i = 0; i < 16; ++i) tmp[i] = Ls[seg * 16 + i][row];
    bf16* dst = vt + ((size_t)bh * 64 + row) * 2048 + s0 + seg * 16;
    *(uint4*)dst = *(uint4*)&tmp[0];
    *(uint4*)(dst + 8) = *(uint4*)&tmp[8];
}

// ---------------- flash attention: S^T/O^T formulation, all K=32 MFMAs, vector LDS/global I/O ----------------
// S^T = K·Q^T  (C lane: kv=quad*4+r, q=l15  — R4-verified layout)
// P^T -> LDS [q][kv] via b64 writes; O^T = V^T·P^T (C lane: d=quad*4+r, q=l15) -> b64 global stores
__global__ __launch_bounds__(256) void attn_k(const bf16* __restrict__ q,
                                              const bf16* __restrict__ k,
                                              const bf16* __restrict__ vt,
                                              bf16* __restrict__ pO,
                                              float* __restrict__ pL) {
    int bh = blockIdx.y;
    int q0 = blockIdx.x * 128;
    int sz = blockIdx.z;
    int kt0 = sz * 16;
    int tid = threadIdx.x;
    int lane = tid & 63, w = tid >> 6;
    int quad = lane >> 4, l15 = lane & 15;
    __shared__ bf16 Ks[64 * 72];
    __shared__ bf16 Vs[64 * 72];
    __shared__ bf16 Ps[128 * 72]; // P^T as [q][kv]
    const bf16* qb = q + (size_t)bh * 2048 * 64;
    const bf16* kb = k + (size_t)bh * 2048 * 64;
    const bf16* vb = vt + (size_t)bh * 64 * 2048;
    bf16x8_t qf[2][2]; // B-operand: n=q(l15), k=d(ks*32+quad*8+j)
#pragma unroll
    for (int qt = 0; qt < 2; ++qt)
#pragma unroll
        for (int ks = 0; ks < 2; ++ks)
            qf[qt][ks] = *(const bf16x8_t*)(qb + (size_t)(q0 + w * 32 + qt * 16 + l15) * 64 + ks * 32 + quad * 8);
    bf16x8_t ones8;
#pragma unroll
    for (int i = 0; i < 8; ++i) ones8[i] = (bf16)1.0f;
    f32x4_t oacc[2][4] = {}; // [qt][dt]: O^T, d=quad*4+r (+16*dt), q=l15 (+16*qt+32*w)
    f32x4_t lacc[2] = {};
    int srow = tid >> 3, ssub = tid & 7;
    uint4 pk[2], pw[2];
    auto gload = [&](int kt) {
        int kbase = kt * 64;
#pragma unroll
        for (int i = 0; i < 2; ++i) {
            int row = i * 32 + srow;
            pk[i] = *(const uint4*)(kb + (size_t)(kbase + row) * 64 + ssub * 8);
            pw[i] = *(const uint4*)(vb + (size_t)row * 2048 + kbase + ssub * 8);
        }
    };
    auto sstore = [&]() {
#pragma unroll
        for (int i = 0; i < 2; ++i) {
            int row = i * 32 + srow;
            *(uint4*)&Ks[row * 72 + ssub * 8] = pk[i];
            *(uint4*)&Vs[row * 72 + ssub * 8] = pw[i];
        }
    };
    gload(kt0);
    for (int kt = kt0; kt < kt0 + 16; ++kt) {
        __syncthreads(); // prev tile's LDS readers done
        sstore();
        __syncthreads();
        if (kt + 1 < kt0 + 16) gload(kt + 1); // latency overlaps compute below
        // S^T = K·Q^T
        f32x4_t sacc[4][2] = {}; // [nt(kv)][qt]
#pragma unroll
        for (int ks = 0; ks < 2; ++ks) {
            int koff = ks * 32 + quad * 8;
            bf16x8_t kf[4]; // A: m=kv(l15), k=d
#pragma unroll
            for (int nt = 0; nt < 4; ++nt)
                kf[nt] = *(const bf16x8_t*)&Ks[(nt * 16 + l15) * 72 + koff];
#pragma unroll
            for (int nt = 0; nt < 4; ++nt)
#pragma unroll
                for (int qt = 0; qt < 2; ++qt)
                    sacc[nt][qt] = MFMA16(kf[nt], qf[qt][ks], sacc[nt][qt]);
        }
        // P^T = exp2(S^T) -> Ps[q][kv], one b64 write per (nt,qt); wave-private rows
#pragma unroll
        for (int nt = 0; nt < 4; ++nt)
#pragma unroll
            for (int qt = 0; qt < 2; ++qt) {
                bf16x4_t pv;
#pragma unroll
                for (int r = 0; r < 4; ++r) pv[r] = (bf16)exp2f(sacc[nt][qt][r]);
                *(bf16x4_t*)&Ps[(w * 32 + qt * 16 + l15) * 72 + nt * 16 + quad * 4] = pv;
            }
        // O^T += V^T·P^T ; l += 1·P^T  (all K=32)
#pragma unroll
        for (int ks = 0; ks < 2; ++ks) {
            int koff = ks * 32 + quad * 8;
            bf16x8_t vf[4], pf[2];
#pragma unroll
            for (int dt = 0; dt < 4; ++dt)
                vf[dt] = *(const bf16x8_t*)&Vs[(dt * 16 + l15) * 72 + koff]; // A: m=d(l15), k=kv
#pragma unroll
            for (int qt = 0; qt < 2; ++qt)
                pf[qt] = *(const bf16x8_t*)&Ps[(w * 32 + qt * 16 + l15) * 72 + koff]; // B: n=q(l15), k=kv
#pragma unroll
            for (int qt = 0; qt < 2; ++qt) {
#pragma unroll
                for (int dt = 0; dt < 4; ++dt)
                    oacc[qt][dt] = MFMA16(vf[dt], pf[qt], oacc[qt][dt]);
                lacc[qt] = MFMA16(ones8, pf[qt], lacc[qt]);
            }
        }
    }
    // write partial O: lane holds 4 consecutive d per (qt,dt) -> b64 stores
    size_t obase = ((size_t)(sz * 32 + bh) * 2048 + q0);
#pragma unroll
    for (int qt = 0; qt < 2; ++qt) {
        int qq = w * 32 + qt * 16 + l15;
#pragma unroll
        for (int dt = 0; dt < 4; ++dt) {
            bf16x4_t ov;
#pragma unroll
            for (int r = 0; r < 4; ++r) ov[r] = (bf16)oacc[qt][dt][r];
            *(bf16x4_t*)&pO[(obase + qq) * 64 + dt * 16 + quad * 4] = ov;
        }
        if (quad == 0) pL[obase + qq] = lacc[qt][0];
    }
}

// ---------------- out-proj GEMM with fused split-combine A-staging ----------------
// A[t,k] = (pO0+pO1)/(l0+l1) at head s = k>>6; C = A*wo^T + bout + xn -> xrf (f32 only)
__global__ __launch_bounds__(256) void gemmo_k(const bf16* __restrict__ pO,
                                               const float* __restrict__ pL,
                                               const bf16* __restrict__ B,
                                               const float* __restrict__ bias,
                                               const bf16* __restrict__ xn,
                                               float* __restrict__ xrf) {
    int m0 = blockIdx.x * 128, n0 = blockIdx.y * 128;
    int tid = threadIdx.x;
    int lane = tid & 63, w = tid >> 6;
    int quad = lane >> 4, l15 = lane & 15;
    int wm = (w >> 1) * 64, wn = (w & 1) * 64;
    __shared__ bf16 As[128 * 72];
    __shared__ bf16 Bs[128 * 72];
    f32x4_t acc[4][4] = {};
    int srow = tid >> 3, ssub = tid & 7;
    const bf16* Bb = B + (size_t)(n0 + srow) * 512 + ssub * 8;
    bf16x8_t pa[4];
    uint4 pb[4];
    auto gload = [&](int s) {
        int k0 = s * 64;
#pragma unroll
        for (int i = 0; i < 4; ++i) {
            int t = m0 + i * 32 + srow;
            int b = t >> 11, ssi = t & 2047;
            size_t r0 = ((size_t)(b * 8 + s)) * 2048 + ssi;
            size_t r1 = ((size_t)(32 + b * 8 + s)) * 2048 + ssi;
            float inv = 1.f / (pL[r0] + pL[r1]);
            bf16x8_t a0 = *(const bf16x8_t*)(pO + r0 * 64 + ssub * 8);
            bf16x8_t a1 = *(const bf16x8_t*)(pO + r1 * 64 + ssub * 8);
            bf16x8_t c;
#pragma unroll
            for (int j = 0; j < 8; ++j) c[j] = (bf16)(((float)a0[j] + (float)a1[j]) * inv);
            pa[i] = c;
            pb[i] = *(const uint4*)(Bb + (size_t)(i * 32) * 512 + k0);
        }
    };
    auto sstore = [&]() {
#pragma unroll
        for (int i = 0; i < 4; ++i) {
            *(bf16x8_t*)&As[(i * 32 + srow) * 72 + ssub * 8] = pa[i];
            *(uint4*)&Bs[(i * 32 + srow) * 72 + ssub * 8] = pb[i];
        }
    };
    gload(0);
    sstore();
    for (int s = 0; s < 8; ++s) {
        __syncthreads();
        if (s < 7) gload(s + 1);
#pragma unroll
        for (int ks = 0; ks < 2; ++ks) {
            bf16x8_t af[4], bfr[4];
            int koff = ks * 32 + quad * 8;
#pragma unroll
            for (int mt = 0; mt < 4; ++mt)
                af[mt] = *(const bf16x8_t*)&As[(wm + mt * 16 + l15) * 72 + koff];
#pragma unroll
            for (int nt = 0; nt < 4; ++nt)
                bfr[nt] = *(const bf16x8_t*)&Bs[(wn + nt * 16 + l15) * 72 + koff];
#pragma unroll
            for (int mt = 0; mt < 4; ++mt)
#pragma unroll
                for (int nt = 0; nt < 4; ++nt)
                    acc[mt][nt] = MFMA16(af[mt], bfr[nt], acc[mt][nt]);
        }
        __syncthreads();
        if (s < 7) sstore();
    }
#pragma unroll
    for (int mt = 0; mt < 4; ++mt) {
#pragma unroll
        for (int nt = 0; nt < 4; ++nt) {
            int gcol = n0 + wn + nt * 16 + l15;
            float bcol = bias[gcol];
#pragma unroll
            for (int r = 0; r < 4; ++r) {
                int grow = m0 + wm + mt * 16 + quad * 4 + r;
                size_t idx = (size_t)grow * 512 + gcol;
                xrf[idx] = acc[mt][nt][r] + bcol + (float)xn[idx];
            }
        }
    }
}

// ---------------- fused MLP gate: h = silu(xrf*w1^T+b1); st = sigmoid(h.w2+b2); out = xrf*st ----------------
__global__ __launch_bounds__(256) void mlp_k(const bf16* __restrict__ B,   // w1b [256,512]
                                             const float* __restrict__ b1,
                                             const float* __restrict__ w2,
                                             const float* __restrict__ b2,
                                             const float* __restrict__ xrf,
                                             float* __restrict__ out) {
    int m0 = blockIdx.x * 32;
    int tid = threadIdx.x;
    int lane = tid & 63, w = tid >> 6;
    int quad = lane >> 4, l15 = lane & 15;
    int wn = w * 64;
    __shared__ bf16 As[32 * 72];
    __shared__ bf16 Bs[256 * 72];
    __shared__ float red[4][32];
    __shared__ float st[32];
    f32x4_t acc[2][4] = {};
    int srow = tid >> 3, ssub = tid & 7;
    bf16x8_t pa;
    uint4 pb[8];
    auto gload = [&](int s) {
        int k0 = s * 64;
        const float* ar = xrf + (size_t)(m0 + srow) * 512 + ssub * 8 + k0;
        float4 f0 = *(const float4*)ar;
        float4 f1 = *(const float4*)(ar + 4);
        pa[0] = (bf16)f0.x; pa[1] = (bf16)f0.y; pa[2] = (bf16)f0.z; pa[3] = (bf16)f0.w;
        pa[4] = (bf16)f1.x; pa[5] = (bf16)f1.y; pa[6] = (bf16)f1.z; pa[7] = (bf16)f1.w;
#pragma unroll
        for (int i = 0; i < 8; ++i)
            pb[i] = *(const uint4*)(B + (size_t)(i * 32 + srow) * 512 + ssub * 8 + k0);
    };
    auto sstore = [&]() {
        *(bf16x8_t*)&As[srow * 72 + ssub * 8] = pa;
#pragma unroll
        for (int i = 0; i < 8; ++i)
            *(uint4*)&Bs[(i * 32 + srow) * 72 + ssub * 8] = pb[i];
    };
    gload(0);
    sstore();
    for (int s = 0; s < 8; ++s) {
        __syncthreads();
        if (s < 7) gload(s + 1);
#pragma unroll
        for (int ks = 0; ks < 2; ++ks) {
            int koff = ks * 32 + quad * 8;
            bf16x8_t af[2], bfr[4];
#pragma unroll
            for (int mt = 0; mt < 2; ++mt)
                af[mt] = *(const bf16x8_t*)&As[(mt * 16 + l15) * 72 + koff];
#pragma unroll
            for (int nt = 0; nt < 4; ++nt)
                bfr[nt] = *(const bf16x8_t*)&Bs[(wn + nt * 16 + l15) * 72 + koff];
#pragma unroll
            for (int mt = 0; mt < 2; ++mt)
#pragma unroll
                for (int nt = 0; nt < 4; ++nt)
                    acc[mt][nt] = MFMA16(af[mt], bfr[nt], acc[mt][nt]);
        }
        __syncthreads();
        if (s < 7) sstore();
    }
    f32x4_t ds[2] = {};
#pragma unroll
    for (int mt = 0; mt < 2; ++mt)
#pragma unroll
        for (int nt = 0; nt < 4; ++nt) {
            int gcol = wn + nt * 16 + l15;
            float bb = b1[gcol], ww = w2[gcol];
#pragma unroll
            for (int r = 0; r < 4; ++r) {
                float v = acc[mt][nt][r] + bb;
                float sv = v / (1.f + __expf(-v));
                ds[mt][r] += sv * ww;
            }
        }
#pragma unroll
    for (int m = 1; m < 16; m <<= 1)
#pragma unroll
        for (int mt = 0; mt < 2; ++mt)
#pragma unroll
            for (int r = 0; r < 4; ++r) ds[mt][r] += __shfl_xor(ds[mt][r], m, 64);
    if (l15 == 0) {
#pragma unroll
        for (int mt = 0; mt < 2; ++mt)
#pragma unroll
            for (int r = 0; r < 4; ++r) red[w][mt * 16 + quad * 4 + r] = ds[mt][r];
    }
    __syncthreads();
    if (tid < 32) {
        float d = red[0][tid] + red[1][tid] + red[2][tid] + red[3][tid] + b2[0];
        st[tid] = 1.f / (1.f + __expf(-d));
    }
    __syncthreads();
    int row = tid >> 3, seg = tid & 7;
    float sr = st[row];
    const float4* x4 = (const float4*)(xrf + (size_t)(m0 + row) * 512);
    float4* o4 = (float4*)(out + (size_t)(m0 + row) * 512);
#pragma unroll
    for (int jj = 0; jj < 16; ++jj) {
        float4 xv = x4[jj * 8 + seg];
        float4 ov;
        ov.x = xv.x * sr; ov.y = xv.y * sr; ov.z = xv.z * sr; ov.w = xv.w * sr;
        o4[jj * 8 + seg] = ov;
    }
}

extern "C" void kernel_launch(void* const* d_in, const int* in_sizes, int n_in,
                              void* d_out, int out_size, void* d_ws, size_t ws_size,
                              hipStream_t stream) {
    const float* x    = (const float*)d_in[0];
    const int*   gt   = (const int*)d_in[1];
    const float* tfg  = (const float*)d_in[2];
    const float* tfb  = (const float*)d_in[3];
    const float* tgg  = (const float*)d_in[4];
    const float* tgb  = (const float*)d_in[5];
    const float* Wqkv = (const float*)d_in[6];
    const float* bqkv = (const float*)d_in[7];
    const float* Wout = (const float*)d_in[8];
    const float* bout = (const float*)d_in[9];
    const float* W1   = (const float*)d_in[10];
    const float* b1   = (const float*)d_in[11];
    const float* w2   = (const float*)d_in[12];
    const float* b2   = (const float*)d_in[13];
    float* out = (float*)d_out;
    char* ws = (char*)d_ws;

    const size_t MB = 1024 * 1024;
    // [0,4MB): weights + row sums
    bf16*  wq  = (bf16*)(ws + 0);                          // 1.5 MB [1536,512]
    bf16*  wo  = (bf16*)(ws + 1536 * 512 * 2);             // 0.5 MB [512,512]
    bf16*  w1b = (bf16*)(ws + (1536 + 512) * 512 * 2);     // 0.25 MB [256,512]
    float* pL  = (float*)(ws + 2304 * 512 * 2);            // 0.5 MB [2][32,2048]
    // activations (aliased by liveness); peak 60 MB
    bf16*  xn  = (bf16*)(ws + 4 * MB);   //  8 MB [8192,512]          live: castln..gemmo
    bf16*  q   = (bf16*)(ws + 12 * MB);  //  8 MB [32,2048,64]        live: gemmqkv..attn
    bf16*  kk  = (bf16*)(ws + 20 * MB);  //  8 MB [32,2048,64]        live: gemmqkv..attn
    float* xrf = (float*)(ws + 12 * MB); // 16 MB [8192,512] (=q,kk)  live: gemmo..mlp
    bf16*  vv  = (bf16*)(ws + 28 * MB);  //  8 MB [32,2048,64]        live: gemmqkv..vtrans
    bf16*  vt  = (bf16*)(ws + 36 * MB);  //  8 MB [32,64,2048]        live: vtrans..attn
    bf16*  pO  = (bf16*)(ws + 44 * MB);  // 16 MB [2][32,2048,64]     live: attn..gemmo

    castln_k<<<6656, 256, 0, stream>>>(Wqkv, Wout, W1, wq, wo, w1b,
                                       x, gt, tfg, tfb, tgg, tgb, xn);
    gemmqkv_k<<<dim3(64, 12), 256, 0, stream>>>(xn, wq, bqkv, q, kk, vv);
    vtrans_k<<<dim3(32, 32), 256, 0, stream>>>(vv, vt);
    attn_k<<<dim3(16, 32, 2), 256, 0, stream>>>(q, kk, vt, pO, pL);
    gemmo_k<<<dim3(64, 4), 256, 0, stream>>>(pO, pL, wo, bout, xn, xrf);
    mlp_k<<<256, 256, 0, stream>>>(w1b, b1, w2, b2, xrf, out);
    (void)in_sizes; (void)n_in; (void)out_size; (void)ws_size;
}

// Round 8
// 314.858 us; speedup vs baseline: 1.0959x; 1.0498x over previous
//
#include <hip/hip_runtime.h>

typedef __bf16 bf16;
typedef __bf16 bf16x4_t __attribute__((ext_vector_type(4)));
typedef __bf16 bf16x8_t __attribute__((ext_vector_type(8)));
typedef float f32x4_t __attribute__((ext_vector_type(4)));

#define MFMA16(a, b, c) __builtin_amdgcn_mfma_f32_16x16x32_bf16(a, b, c, 0, 0, 0)

// ---------------- fused: weight casts (blocks 0..4607) + conditional LN (4608..6655) ----------------
__global__ __launch_bounds__(256) void castln_k(const float* __restrict__ Wqkv,
                                                const float* __restrict__ Wout,
                                                const float* __restrict__ W1,
                                                bf16* __restrict__ wq,
                                                bf16* __restrict__ wo,
                                                bf16* __restrict__ w1b,
                                                const float* __restrict__ x,
                                                const int* __restrict__ gt,
                                                const float* __restrict__ tfg,
                                                const float* __restrict__ tfb,
                                                const float* __restrict__ tgg,
                                                const float* __restrict__ tgb,
                                                bf16* __restrict__ xn) {
    if (blockIdx.x < 4608) {
        int i = blockIdx.x * 256 + threadIdx.x;
        if (i < 786432) wq[i] = (bf16)Wqkv[i];
        else if (i < 1048576) wo[i - 786432] = (bf16)Wout[i - 786432];
        else if (i < 1179648) w1b[i - 1048576] = (bf16)W1[i - 1048576];
        return;
    }
    int wid = threadIdx.x >> 6, lane = threadIdx.x & 63;
    int t = (blockIdx.x - 4608) * 4 + wid;
    const float4* xr = (const float4*)(x + (size_t)t * 512);
    float4 a = xr[lane * 2], b = xr[lane * 2 + 1];
    float s = (a.x + a.y) + (a.z + a.w) + (b.x + b.y) + (b.z + b.w);
    float sq = a.x * a.x + a.y * a.y + a.z * a.z + a.w * a.w +
               b.x * b.x + b.y * b.y + b.z * b.z + b.w * b.w;
    for (int m = 1; m < 64; m <<= 1) {
        s += __shfl_xor(s, m, 64);
        sq += __shfl_xor(sq, m, 64);
    }
    float mean = s * (1.f / 512.f);
    float var = fmaxf(sq * (1.f / 512.f) - mean * mean, 0.f);
    float rstd = rsqrtf(var + 1e-5f);
    int g = gt[t];
    float4 o0, o1;
    if (g < 2) {
        const float4* gp = (const float4*)(g ? tgg : tfg);
        const float4* bp = (const float4*)(g ? tgb : tfb);
        float4 g0 = gp[lane * 2], g1 = gp[lane * 2 + 1];
        float4 b0 = bp[lane * 2], b1 = bp[lane * 2 + 1];
        o0.x = (a.x - mean) * rstd * g0.x + b0.x;
        o0.y = (a.y - mean) * rstd * g0.y + b0.y;
        o0.z = (a.z - mean) * rstd * g0.z + b0.z;
        o0.w = (a.w - mean) * rstd * g0.w + b0.w;
        o1.x = (b.x - mean) * rstd * g1.x + b1.x;
        o1.y = (b.y - mean) * rstd * g1.y + b1.y;
        o1.z = (b.z - mean) * rstd * g1.z + b1.z;
        o1.w = (b.w - mean) * rstd * g1.w + b1.w;
    } else {
        o0 = a; o1 = b;
    }
    bf16* xo = xn + (size_t)t * 512 + lane * 8;
    bf16x4_t p0, p1;
    p0[0] = (bf16)o0.x; p0[1] = (bf16)o0.y; p0[2] = (bf16)o0.z; p0[3] = (bf16)o0.w;
    p1[0] = (bf16)o1.x; p1[1] = (bf16)o1.y; p1[2] = (bf16)o1.z; p1[3] = (bf16)o1.w;
    *(bf16x4_t*)xo = p0;
    *(bf16x4_t*)(xo + 4) = p1;
}

// ---------------- QKV GEMM + fused V transpose ----------------
// blocks by<8: q/k epilogue [BH,S,64]; by>=8: V tile transposed in-LDS, vt [BH,64,S] coalesced
__global__ __launch_bounds__(256) void gemmqkv_k(const bf16* __restrict__ A,
                                                 const bf16* __restrict__ B,
                                                 const float* __restrict__ bias,
                                                 bf16* __restrict__ q,
                                                 bf16* __restrict__ kk,
                                                 bf16* __restrict__ vt) {
    int m0 = blockIdx.x * 128, n0 = blockIdx.y * 128;
    int tid = threadIdx.x;
    int lane = tid & 63, w = tid >> 6;
    int quad = lane >> 4, l15 = lane & 15;
    int wm = (w >> 1) * 64, wn = (w & 1) * 64;
    __shared__ bf16 smem[128 * 144]; // As | Bs, reused as Ts (128x136) for V transpose
    bf16* As = smem;
    bf16* Bs = smem + 128 * 72;
    f32x4_t acc[4][4] = {};
    int srow = tid >> 3, ssub = tid & 7;
    const bf16* Ab = A + (size_t)(m0 + srow) * 512 + ssub * 8;
    const bf16* Bb = B + (size_t)(n0 + srow) * 512 + ssub * 8;
    uint4 pa[4], pb[4];
    auto gload = [&](int s) {
        int k0 = s * 64;
#pragma unroll
        for (int i = 0; i < 4; ++i) {
            pa[i] = *(const uint4*)(Ab + (size_t)(i * 32) * 512 + k0);
            pb[i] = *(const uint4*)(Bb + (size_t)(i * 32) * 512 + k0);
        }
    };
    auto sstore = [&]() {
#pragma unroll
        for (int i = 0; i < 4; ++i) {
            *(uint4*)&As[(i * 32 + srow) * 72 + ssub * 8] = pa[i];
            *(uint4*)&Bs[(i * 32 + srow) * 72 + ssub * 8] = pb[i];
        }
    };
    gload(0);
    sstore();
    for (int s = 0; s < 8; ++s) {
        __syncthreads();
        if (s < 7) gload(s + 1);
#pragma unroll
        for (int ks = 0; ks < 2; ++ks) {
            bf16x8_t af[4], bfr[4];
            int koff = ks * 32 + quad * 8;
#pragma unroll
            for (int mt = 0; mt < 4; ++mt)
                af[mt] = *(const bf16x8_t*)&As[(wm + mt * 16 + l15) * 72 + koff];
#pragma unroll
            for (int nt = 0; nt < 4; ++nt)
                bfr[nt] = *(const bf16x8_t*)&Bs[(wn + nt * 16 + l15) * 72 + koff];
#pragma unroll
            for (int mt = 0; mt < 4; ++mt)
#pragma unroll
                for (int nt = 0; nt < 4; ++nt)
                    acc[mt][nt] = MFMA16(af[mt], bfr[nt], acc[mt][nt]);
        }
        __syncthreads();
        if (s < 7) sstore();
    }
    if (blockIdx.y < 8) {
        // q / k epilogue (gcol < 1024)
#pragma unroll
        for (int mt = 0; mt < 4; ++mt) {
#pragma unroll
            for (int nt = 0; nt < 4; ++nt) {
                int gcol = n0 + wn + nt * 16 + l15;
                float bcol = bias[gcol];
#pragma unroll
                for (int r = 0; r < 4; ++r) {
                    int grow = m0 + wm + mt * 16 + quad * 4 + r;
                    float v = acc[mt][nt][r] + bcol;
                    int d = gcol & 511;
                    int hh = d >> 6, hd = d & 63;
                    int b = grow >> 11, ssi = grow & 2047;
                    size_t idx = (((size_t)(b * 8 + hh)) * 2048 + ssi) * 64 + hd;
                    if (gcol < 512) q[idx] = (bf16)(v * 0.180336880111f); // 0.125*log2(e)
                    else kk[idx] = (bf16)v;
                }
            }
        }
    } else {
        // V tile: stage to Ts[token][d] (stride 136), then write vt coalesced along S
        __syncthreads(); // all waves done reading As/Bs
#pragma unroll
        for (int mt = 0; mt < 4; ++mt)
#pragma unroll
            for (int nt = 0; nt < 4; ++nt) {
                int gcol = n0 + wn + nt * 16 + l15;
                float bcol = bias[gcol];
#pragma unroll
                for (int r = 0; r < 4; ++r) {
                    int tok = wm + mt * 16 + quad * 4 + r;
                    smem[tok * 136 + wn + nt * 16 + l15] = (bf16)(acc[mt][nt][r] + bcol);
                }
            }
        __syncthreads();
        int dl = tid >> 1, seg = tid & 1; // d-local 0..127, token half
        int d = (n0 - 1024) + dl;
        int hh = d >> 6, hd = d & 63;
        int b = m0 >> 11, ssi0 = m0 & 2047;
        bf16* dst = vt + ((size_t)(b * 8 + hh) * 64 + hd) * 2048 + ssi0 + seg * 64;
#pragma unroll
        for (int u = 0; u < 8; ++u) {
            bf16 tmp[8];
#pragma unroll
            for (int j = 0; j < 8; ++j) tmp[j] = smem[(seg * 64 + u * 8 + j) * 136 + dl];
            *(uint4*)(dst + u * 8) = *(uint4*)tmp;
        }
    }
}

// ---------------- flash attention: R3-verbatim compute (95.7 us proven), templated KV split ----------------
// q,k: [BH,S,64] (q pre-scaled by 0.125*log2e); vt: [BH,64,S]
// pO: [NSPLIT][BH,S,64] bf16 un-normalized; pL: [NSPLIT][BH,S] f32 row sums
template <int TILES>
__global__ __launch_bounds__(256) void attn_k(const bf16* __restrict__ q,
                                              const bf16* __restrict__ k,
                                              const bf16* __restrict__ vt,
                                              bf16* __restrict__ pO,
                                              float* __restrict__ pL) {
    int bh = blockIdx.y;
    int q0 = blockIdx.x * 128;
    int sz = blockIdx.z;
    int tid = threadIdx.x;
    int lane = tid & 63, w = tid >> 6;
    int quad = lane >> 4, l15 = lane & 15;
    __shared__ bf16 Ks[64 * 72];
    __shared__ bf16 Vs[64 * 72];
    __shared__ bf16 Ps[128 * 72];
    const bf16* qb = q + (size_t)bh * 2048 * 64;
    const bf16* kb = k + (size_t)bh * 2048 * 64;
    const bf16* vb = vt + (size_t)bh * 64 * 2048;
    bf16x8_t qf[2][2];
#pragma unroll
    for (int mt = 0; mt < 2; ++mt)
#pragma unroll
        for (int ks = 0; ks < 2; ++ks)
            qf[mt][ks] = *(const bf16x8_t*)(qb + (size_t)(q0 + w * 32 + mt * 16 + l15) * 64 + ks * 32 + quad * 8);
    bf16x8_t ones8;
#pragma unroll
    for (int i = 0; i < 8; ++i) ones8[i] = (bf16)1.0f;
    f32x4_t oacc[2][4] = {};
    f32x4_t lacc[2] = {};
    int srow = tid >> 3, ssub = tid & 7;
    for (int kt = sz * TILES; kt < sz * TILES + TILES; ++kt) {
        int kbase = kt * 64;
        __syncthreads();
#pragma unroll
        for (int i = 0; i < 2; ++i) {
            int row = i * 32 + srow;
            *(uint4*)&Ks[row * 72 + ssub * 8] = *(const uint4*)(kb + (size_t)(kbase + row) * 64 + ssub * 8);
            *(uint4*)&Vs[row * 72 + ssub * 8] = *(const uint4*)(vb + (size_t)row * 2048 + kbase + ssub * 8);
        }
        __syncthreads();
        // S = Q K^T (log2-domain scale folded into q)
        f32x4_t sacc[2][4] = {};
#pragma unroll
        for (int ks = 0; ks < 2; ++ks) {
            bf16x8_t kf[4];
            int koff = ks * 32 + quad * 8;
#pragma unroll
            for (int nt = 0; nt < 4; ++nt) kf[nt] = *(const bf16x8_t*)&Ks[(nt * 16 + l15) * 72 + koff];
#pragma unroll
            for (int mt = 0; mt < 2; ++mt)
#pragma unroll
                for (int nt = 0; nt < 4; ++nt)
                    sacc[mt][nt] = MFMA16(qf[mt][ks], kf[nt], sacc[mt][nt]);
        }
        // P = exp2(S), straight to LDS in A-operand layout (wave-private rows)
#pragma unroll
        for (int mt = 0; mt < 2; ++mt)
#pragma unroll
            for (int nt = 0; nt < 4; ++nt)
#pragma unroll
                for (int r = 0; r < 4; ++r)
                    Ps[(w * 32 + mt * 16 + quad * 4 + r) * 72 + nt * 16 + l15] = (bf16)exp2f(sacc[mt][nt][r]);
        // O += P V ; l += P . 1 (row sums via MFMA with all-ones B)
#pragma unroll
        for (int ks = 0; ks < 2; ++ks) {
            int koff = ks * 32 + quad * 8;
            bf16x8_t pf[2], vf[4];
#pragma unroll
            for (int mt = 0; mt < 2; ++mt) pf[mt] = *(const bf16x8_t*)&Ps[(w * 32 + mt * 16 + l15) * 72 + koff];
#pragma unroll
            for (int nt = 0; nt < 4; ++nt) vf[nt] = *(const bf16x8_t*)&Vs[(nt * 16 + l15) * 72 + koff];
#pragma unroll
            for (int mt = 0; mt < 2; ++mt) {
#pragma unroll
                for (int nt = 0; nt < 4; ++nt)
                    oacc[mt][nt] = MFMA16(pf[mt], vf[nt], oacc[mt][nt]);
                lacc[mt] = MFMA16(pf[mt], ones8, lacc[mt]);
            }
        }
    }
    size_t obase = ((size_t)(sz * 32 + bh) * 2048 + q0);
#pragma unroll
    for (int mt = 0; mt < 2; ++mt)
#pragma unroll
        for (int r = 0; r < 4; ++r) {
            int row = w * 32 + mt * 16 + quad * 4 + r;
#pragma unroll
            for (int nt = 0; nt < 4; ++nt)
                pO[(obase + row) * 64 + nt * 16 + l15] = (bf16)oacc[mt][nt][r];
            if (l15 == 0) pL[obase + row] = lacc[mt][r];
        }
}

// ---------------- out-proj GEMM with fused split-combine A-staging ----------------
template <int NSPLIT>
__global__ __launch_bounds__(256) void gemmo_k(const bf16* __restrict__ pO,
                                               const float* __restrict__ pL,
                                               const bf16* __restrict__ B,
                                               const float* __restrict__ bias,
                                               const bf16* __restrict__ xn,
                                               float* __restrict__ xrf) {
    int m0 = blockIdx.x * 128, n0 = blockIdx.y * 128;
    int tid = threadIdx.x;
    int lane = tid & 63, w = tid >> 6;
    int quad = lane >> 4, l15 = lane & 15;
    int wm = (w >> 1) * 64, wn = (w & 1) * 64;
    __shared__ bf16 As[128 * 72];
    __shared__ bf16 Bs[128 * 72];
    f32x4_t acc[4][4] = {};
    int srow = tid >> 3, ssub = tid & 7;
    const bf16* Bb = B + (size_t)(n0 + srow) * 512 + ssub * 8;
    bf16x8_t pa[4];
    uint4 pb[4];
    auto gload = [&](int s) {
        int k0 = s * 64;
#pragma unroll
        for (int i = 0; i < 4; ++i) {
            int t = m0 + i * 32 + srow;
            int b = t >> 11, ssi = t & 2047;
            float lsum = 0.f;
            float facc[8] = {};
#pragma unroll
            for (int sp = 0; sp < NSPLIT; ++sp) {
                size_t r = ((size_t)(sp * 32 + b * 8 + s)) * 2048 + ssi;
                lsum += pL[r];
                bf16x8_t av = *(const bf16x8_t*)(pO + r * 64 + ssub * 8);
#pragma unroll
                for (int j = 0; j < 8; ++j) facc[j] += (float)av[j];
            }
            float inv = 1.f / lsum;
            bf16x8_t c;
#pragma unroll
            for (int j = 0; j < 8; ++j) c[j] = (bf16)(facc[j] * inv);
            pa[i] = c;
            pb[i] = *(const uint4*)(Bb + (size_t)(i * 32) * 512 + k0);
        }
    };
    auto sstore = [&]() {
#pragma unroll
        for (int i = 0; i < 4; ++i) {
            *(bf16x8_t*)&As[(i * 32 + srow) * 72 + ssub * 8] = pa[i];
            *(uint4*)&Bs[(i * 32 + srow) * 72 + ssub * 8] = pb[i];
        }
    };
    gload(0);
    sstore();
    for (int s = 0; s < 8; ++s) {
        __syncthreads();
        if (s < 7) gload(s + 1);
#pragma unroll
        for (int ks = 0; ks < 2; ++ks) {
            bf16x8_t af[4], bfr[4];
            int koff = ks * 32 + quad * 8;
#pragma unroll
            for (int mt = 0; mt < 4; ++mt)
                af[mt] = *(const bf16x8_t*)&As[(wm + mt * 16 + l15) * 72 + koff];
#pragma unroll
            for (int nt = 0; nt < 4; ++nt)
                bfr[nt] = *(const bf16x8_t*)&Bs[(wn + nt * 16 + l15) * 72 + koff];
#pragma unroll
            for (int mt = 0; mt < 4; ++mt)
#pragma unroll
                for (int nt = 0; nt < 4; ++nt)
                    acc[mt][nt] = MFMA16(af[mt], bfr[nt], acc[mt][nt]);
        }
        __syncthreads();
        if (s < 7) sstore();
    }
#pragma unroll
    for (int mt = 0; mt < 4; ++mt) {
#pragma unroll
        for (int nt = 0; nt < 4; ++nt) {
            int gcol = n0 + wn + nt * 16 + l15;
            float bcol = bias[gcol];
#pragma unroll
            for (int r = 0; r < 4; ++r) {
                int grow = m0 + wm + mt * 16 + quad * 4 + r;
                size_t idx = (size_t)grow * 512 + gcol;
                xrf[idx] = acc[mt][nt][r] + bcol + (float)xn[idx];
            }
        }
    }
}

// ---------------- fused MLP gate: h = silu(xrf*w1^T+b1); st = sigmoid(h.w2+b2); out = xrf*st ----------------
__global__ __launch_bounds__(256) void mlp_k(const bf16* __restrict__ B,   // w1b [256,512]
                                             const float* __restrict__ b1,
                                             const float* __restrict__ w2,
                                             const float* __restrict__ b2,
                                             const float* __restrict__ xrf,
                                             float* __restrict__ out) {
    int m0 = blockIdx.x * 32;
    int tid = threadIdx.x;
    int lane = tid & 63, w = tid >> 6;
    int quad = lane >> 4, l15 = lane & 15;
    int wn = w * 64;
    __shared__ bf16 As[32 * 72];
    __shared__ bf16 Bs[256 * 72];
    __shared__ float red[4][32];
    __shared__ float st[32];
    f32x4_t acc[2][4] = {};
    int srow = tid >> 3, ssub = tid & 7;
    bf16x8_t pa;
    uint4 pb[8];
    auto gload = [&](int s) {
        int k0 = s * 64;
        const float* ar = xrf + (size_t)(m0 + srow) * 512 + ssub * 8 + k0;
        float4 f0 = *(const float4*)ar;
        float4 f1 = *(const float4*)(ar + 4);
        pa[0] = (bf16)f0.x; pa[1] = (bf16)f0.y; pa[2] = (bf16)f0.z; pa[3] = (bf16)f0.w;
        pa[4] = (bf16)f1.x; pa[5] = (bf16)f1.y; pa[6] = (bf16)f1.z; pa[7] = (bf16)f1.w;
#pragma unroll
        for (int i = 0; i < 8; ++i)
            pb[i] = *(const uint4*)(B + (size_t)(i * 32 + srow) * 512 + ssub * 8 + k0);
    };
    auto sstore = [&]() {
        *(bf16x8_t*)&As[srow * 72 + ssub * 8] = pa;
#pragma unroll
        for (int i = 0; i < 8; ++i)
            *(uint4*)&Bs[(i * 32 + srow) * 72 + ssub * 8] = pb[i];
    };
    gload(0);
    sstore();
    for (int s = 0; s < 8; ++s) {
        __syncthreads();
        if (s < 7) gload(s + 1);
#pragma unroll
        for (int ks = 0; ks < 2; ++ks) {
            int koff = ks * 32 + quad * 8;
            bf16x8_t af[2], bfr[4];
#pragma unroll
            for (int mt = 0; mt < 2; ++mt)
                af[mt] = *(const bf16x8_t*)&As[(mt * 16 + l15) * 72 + koff];
#pragma unroll
            for (int nt = 0; nt < 4; ++nt)
                bfr[nt] = *(const bf16x8_t*)&Bs[(wn + nt * 16 + l15) * 72 + koff];
#pragma unroll
            for (int mt = 0; mt < 2; ++mt)
#pragma unroll
                for (int nt = 0; nt < 4; ++nt)
                    acc[mt][nt] = MFMA16(af[mt], bfr[nt], acc[mt][nt]);
        }
        __syncthreads();
        if (s < 7) sstore();
    }
    f32x4_t ds[2] = {};
#pragma unroll
    for (int mt = 0; mt < 2; ++mt)
#pragma unroll
        for (int nt = 0; nt < 4; ++nt) {
            int gcol = wn + nt * 16 + l15;
            float bb = b1[gcol], ww = w2[gcol];
#pragma unroll
            for (int r = 0; r < 4; ++r) {
                float v = acc[mt][nt][r] + bb;
                float sv = v / (1.f + __expf(-v));
                ds[mt][r] += sv * ww;
            }
        }
#pragma unroll
    for (int m = 1; m < 16; m <<= 1)
#pragma unroll
        for (int mt = 0; mt < 2; ++mt)
#pragma unroll
            for (int r = 0; r < 4; ++r) ds[mt][r] += __shfl_xor(ds[mt][r], m, 64);
    if (l15 == 0) {
#pragma unroll
        for (int mt = 0; mt < 2; ++mt)
#pragma unroll
            for (int r = 0; r < 4; ++r) red[w][mt * 16 + quad * 4 + r] = ds[mt][r];
    }
    __syncthreads();
    if (tid < 32) {
        float d = red[0][tid] + red[1][tid] + red[2][tid] + red[3][tid] + b2[0];
        st[tid] = 1.f / (1.f + __expf(-d));
    }
    __syncthreads();
    int row = tid >> 3, seg = tid & 7;
    float sr = st[row];
    const float4* x4 = (const float4*)(xrf + (size_t)(m0 + row) * 512);
    float4* o4 = (float4*)(out + (size_t)(m0 + row) * 512);
#pragma unroll
    for (int jj = 0; jj < 16; ++jj) {
        float4 xv = x4[jj * 8 + seg];
        float4 ov;
        ov.x = xv.x * sr; ov.y = xv.y * sr; ov.z = xv.z * sr; ov.w = xv.w * sr;
        o4[jj * 8 + seg] = ov;
    }
}

extern "C" void kernel_launch(void* const* d_in, const int* in_sizes, int n_in,
                              void* d_out, int out_size, void* d_ws, size_t ws_size,
                              hipStream_t stream) {
    const float* x    = (const float*)d_in[0];
    const int*   gt   = (const int*)d_in[1];
    const float* tfg  = (const float*)d_in[2];
    const float* tfb  = (const float*)d_in[3];
    const float* tgg  = (const float*)d_in[4];
    const float* tgb  = (const float*)d_in[5];
    const float* Wqkv = (const float*)d_in[6];
    const float* bqkv = (const float*)d_in[7];
    const float* Wout = (const float*)d_in[8];
    const float* bout = (const float*)d_in[9];
    const float* W1   = (const float*)d_in[10];
    const float* b1   = (const float*)d_in[11];
    const float* w2   = (const float*)d_in[12];
    const float* b2   = (const float*)d_in[13];
    float* out = (float*)d_out;
    char* ws = (char*)d_ws;

    const size_t MB = 1024 * 1024;
    // [0,4MB): weights + row sums
    bf16*  wq  = (bf16*)(ws + 0);                          // 1.5 MB [1536,512]
    bf16*  wo  = (bf16*)(ws + 1536 * 512 * 2);             // 0.5 MB [512,512]
    bf16*  w1b = (bf16*)(ws + (1536 + 512) * 512 * 2);     // 0.25 MB [256,512]
    float* pL  = (float*)(ws + 2304 * 512 * 2);            // <=1 MB [nsplit][32,2048]
    // activations (aliased by liveness)
    bf16*  xn  = (bf16*)(ws + 4 * MB);   //  8 MB [8192,512]          live: castln..gemmo
    bf16*  q   = (bf16*)(ws + 12 * MB);  //  8 MB [32,2048,64]        live: gemmqkv..attn
    bf16*  kk  = (bf16*)(ws + 20 * MB);  //  8 MB [32,2048,64]        live: gemmqkv..attn
    float* xrf = (float*)(ws + 12 * MB); // 16 MB [8192,512] (=q,kk)  live: gemmo..mlp
    bf16*  vt  = (bf16*)(ws + 28 * MB);  //  8 MB [32,64,2048]        live: gemmqkv..attn
    bf16*  pO  = (bf16*)(ws + 36 * MB);  //  8*nsplit MB              live: attn..gemmo

    castln_k<<<6656, 256, 0, stream>>>(Wqkv, Wout, W1, wq, wo, w1b,
                                       x, gt, tfg, tfb, tgg, tgb, xn);
    gemmqkv_k<<<dim3(64, 12), 256, 0, stream>>>(xn, wq, bqkv, q, kk, vt);
    if (ws_size >= 69 * MB) { // nsplit=4 (R4 evidence: ws is large enough; constant across calls)
        attn_k<8><<<dim3(16, 32, 4), 256, 0, stream>>>(q, kk, vt, pO, pL);
        gemmo_k<4><<<dim3(64, 4), 256, 0, stream>>>(pO, pL, wo, bout, xn, xrf);
    } else {
        attn_k<16><<<dim3(16, 32, 2), 256, 0, stream>>>(q, kk, vt, pO, pL);
        gemmo_k<2><<<dim3(64, 4), 256, 0, stream>>>(pO, pL, wo, bout, xn, xrf);
    }
    mlp_k<<<256, 256, 0, stream>>>(w1b, b1, w2, b2, xrf, out);
    (void)in_sizes; (void)n_in; (void)out_size;
}